// Round 1
// baseline (505.882 us; speedup 1.0000x reference)
//
#include <hip/hip_runtime.h>
#include <hip/hip_bf16.h>
#include <math.h>

#define N_SAMPLES 32768
#define WINDOW 512
#define STEP 256
#define N_FRAMES 128
#define N_COEFFS 257
#define KPAD 260          // pad to multiple of 4 for float4 LDS reads
#define CPD 16
#define N_RES 32
#define EXPR 4
#define CTRL 128
#define NBN 8             // 2*4 batch*channels
#define PI_F 3.14159265358979323846f

// ---------------------------------------------------------------- K0: per-(r,e,k) params
__global__ __launch_bounds__(256) void k0_params(const float* __restrict__ amp,
                                                 const float* __restrict__ phase,
                                                 const float* __restrict__ decay,
                                                 float* __restrict__ Cre, float* __restrict__ Cim,
                                                 float* __restrict__ Dk, float* __restrict__ L2d) {
    int idx = blockIdx.x * 256 + threadIdx.x;
    int total = N_RES * EXPR * KPAD;
    if (idx >= total) return;
    int k  = idx % KPAD;
    int re = idx / KPAD;            // r*EXPR+e
    int r = re / EXPR, e = re % EXPR;
    if (k >= N_COEFFS) { Cre[idx] = 0.f; Cim[idx] = 0.f; Dk[idx] = 0.f; L2d[idx] = 0.f; return; }
    int src = (r * N_COEFFS + k) * EXPR + e;   // amp is (32,257,4); transpose handled by indexing
    float m  = fabsf(amp[src]) + 1e-12f;       // exp(log(|a|+1e-12)) = |a|+1e-12
    float ph = tanhf(phase[src]) * PI_F;
    float sg = 1.0f / (1.0f + expf(-decay[src]));
    float d  = 0.5f + 0.45f * sg;              // BASE_RES + sigmoid*0.5*0.9
    float wk = (k == 0 || k == 256) ? (1.0f / 512.0f) : (2.0f / 512.0f);  // irfft weights
    Cre[idx] = wk * m * cosf(ph);
    Cim[idx] = wk * m * sinf(ph);
    Dk[idx]  = d;
    L2d[idx] = log2f(d);
}

// ---------------------------------------------------------------- K1: materialize resonances (DFT w/ rotation recurrence)
__global__ __launch_bounds__(256) void k1_res(const float* __restrict__ Cre, const float* __restrict__ Cim,
                                              const float* __restrict__ Dk, const float* __restrict__ L2d,
                                              float* __restrict__ res_raw) {
    __shared__ __align__(16) float2 P[KPAD];
    int blk = blockIdx.x;            // re*N_FRAMES + j
    int j  = blk % N_FRAMES;
    int re = blk / N_FRAMES;
    int tid = threadIdx.x;
    float jf = (float)j;
    for (int k = tid; k < KPAD; k += 256) {
        int gi = re * KPAD + k;
        float pw = exp2f(jf * L2d[gi]);                       // d^j
        float sg = (j >= 1) ? ((k & 1) ? -1.0f : 1.0f) : 0.0f; // OLA second-half term
        float scale = pw * (Dk[gi] + sg);                      // d^j * (d + (-1)^k [j>=1])
        P[k] = make_float2(Cre[gi] * scale, Cim[gi] * scale);
    }
    __syncthreads();
    int o = tid;
    float s1, c1;
    sincosf((float)o * (PI_F / 256.0f), &s1, &c1);   // e^{i*2*pi*o/512}
    float cr = 1.0f, ci = 0.0f;                      // e^{i*2*pi*k*o/512}, k=0
    float acc = 0.0f;
    for (int k = 0; k < KPAD; k += 4) {
        float4 p01 = *reinterpret_cast<const float4*>(&P[k]);
        float4 p23 = *reinterpret_cast<const float4*>(&P[k + 2]);
        acc += p01.x * cr - p01.y * ci;
        { float n = cr * c1 - ci * s1; ci = ci * c1 + cr * s1; cr = n; }
        acc += p01.z * cr - p01.w * ci;
        { float n = cr * c1 - ci * s1; ci = ci * c1 + cr * s1; cr = n; }
        acc += p23.x * cr - p23.y * ci;
        { float n = cr * c1 - ci * s1; ci = ci * c1 + cr * s1; cr = n; }
        acc += p23.z * cr - p23.w * ci;
        { float n = cr * c1 - ci * s1; ci = ci * c1 + cr * s1; cr = n; }
    }
    res_raw[re * N_SAMPLES + j * STEP + o] = acc;
}

// ---------------------------------------------------------------- K2: inverse norms
__global__ __launch_bounds__(256) void k2_norm(const float* __restrict__ res_raw, float* __restrict__ inv_norm) {
    __shared__ float red[256];
    int re = blockIdx.x;
    const float* p = res_raw + (size_t)re * N_SAMPLES;
    float s = 0.f;
    for (int i = threadIdx.x; i < N_SAMPLES; i += 256) { float v = p[i]; s += v * v; }
    red[threadIdx.x] = s;
    __syncthreads();
    for (int st = 128; st > 0; st >>= 1) {
        if (threadIdx.x < st) red[threadIdx.x] += red[threadIdx.x + st];
        __syncthreads();
    }
    if (threadIdx.x == 0) inv_norm[re] = 1.0f / (sqrtf(red[0]) + 1e-8f);
}

// ---------------------------------------------------------------- K3: impulse FIR -> G (float4 over e)
__global__ __launch_bounds__(256) void k3_impconv(const float* __restrict__ res_raw,
                                                  const float* __restrict__ inv_norm,
                                                  const float* __restrict__ noise,
                                                  float4* __restrict__ G4) {
    __shared__ float st[EXPR][384];
    __shared__ float imp[128];
    int blk = blockIdx.x;            // r*N_FRAMES + j
    int j = blk % N_FRAMES;
    int r = blk / N_FRAMES;
    int tid = threadIdx.x;
    for (int i = tid; i < EXPR * 384; i += 256) {
        int e = i / 384, ii = i % 384;
        int g = j * STEP - 127 + ii;
        float v = 0.f;
        if (g >= 0 && g < N_SAMPLES) v = res_raw[(size_t)(r * EXPR + e) * N_SAMPLES + g] * inv_norm[r * EXPR + e];
        st[e][ii] = v;
    }
    if (tid < 128)
        imp[tid] = (0.54f - 0.46f * cosf((2.0f * PI_F / 128.0f) * (float)tid)) * noise[tid];
    __syncthreads();
    float a0 = 0.f, a1 = 0.f, a2 = 0.f, a3 = 0.f;
    #pragma unroll 4
    for (int u = 0; u < 128; ++u) {
        float w = imp[u];
        int idx = tid + 127 - u;
        a0 = fmaf(w, st[0][idx], a0);
        a1 = fmaf(w, st[1][idx], a1);
        a2 = fmaf(w, st[2][idx], a2);
        a3 = fmaf(w, st[3][idx], a3);
    }
    G4[(size_t)r * N_SAMPLES + j * STEP + tid] = make_float4(a0, a1, a2, a3);
}

// ---------------------------------------------------------------- K4a: routed weights (also = before_upsample output)
__global__ __launch_bounds__(256) void k4a_route(const float* __restrict__ control,
                                                 const float* __restrict__ router,
                                                 float* __restrict__ out_w) {
    int idx = blockIdx.x * 256 + threadIdx.x;     // (bn*32+r)*128+f
    int f  = idx % CTRL;
    int r  = (idx / CTRL) % N_RES;
    int bn = idx / (CTRL * N_RES);
    float s = 0.f;
    #pragma unroll
    for (int c = 0; c < CPD; ++c)
        s += control[(bn * CPD + c) * CTRL + f] * router[c * N_RES + r];
    out_w[idx] = s;
}

// ---------------------------------------------------------------- K4b: softmax over expressions per ctrl frame
__global__ __launch_bounds__(256) void k4b_dfr(const float* __restrict__ defo, float* __restrict__ d_frames) {
    int idx = blockIdx.x * 256 + threadIdx.x;    // bn*128+f
    if (idx >= NBN * CTRL) return;
    int f = idx % CTRL, bn = idx / CTRL;
    float v[EXPR]; float mx = -1e30f;
    #pragma unroll
    for (int e = 0; e < EXPR; ++e) {
        float x = defo[(bn * EXPR + e) * CTRL + f] + (e == 0 ? 1.0f : 0.0f);
        v[e] = x; mx = fmaxf(mx, x);
    }
    float sum = 0.f;
    #pragma unroll
    for (int e = 0; e < EXPR; ++e) { v[e] = expf(v[e] - mx); sum += v[e]; }
    float inv = 1.0f / sum;
    #pragma unroll
    for (int e = 0; e < EXPR; ++e) d_frames[(bn * EXPR + e) * CTRL + f] = v[e] * inv;
}

// ---------------------------------------------------------------- K5: spike-train conv + expression mix, all 8 (b,n) per block
__global__ __launch_bounds__(256) void k5_conv(const float4* __restrict__ G4,
                                               const float* __restrict__ out_w,
                                               const float* __restrict__ d_frames,
                                               __hip_bfloat16* __restrict__ xout) {
    __shared__ float wsm[NBN * CTRL];        // w[bn][f] for this r
    __shared__ float dloc[NBN][EXPR][3];     // d_frames at j-1, j, j+1 (clamped)
    int bid = blockIdx.x;                    // 4096
    // XCD-aware swizzle: 8 XCDs round-robin on bid%8 -> give each XCD 4 consecutive r values
    int xcd = bid & 7;
    int y   = bid >> 3;                      // 0..511
    int r   = xcd * 4 + (y & 3);
    int j   = y >> 2;
    int o = threadIdx.x;
    for (int i = o; i < NBN * CTRL; i += 256) {
        int bn = i >> 7, f = i & 127;
        wsm[i] = out_w[(bn * N_RES + r) * CTRL + f];
    }
    if (o < NBN * EXPR * 3) {
        int bn = o / 12, rem = o % 12, e = rem / 3, wch = rem % 3;
        int fr = j - 1 + wch;
        fr = fr < 0 ? 0 : (fr > 127 ? 127 : fr);
        dloc[bn][e][wch] = d_frames[(bn * EXPR + e) * CTRL + fr];
    }
    __syncthreads();
    // interpolation weights for this sample
    float pos = ((float)(j * STEP + o) + 0.5f) * (1.0f / 256.0f) - 0.5f;
    pos = fminf(fmaxf(pos, 0.0f), 127.0f);
    int lo = (int)floorf(pos);
    int hi = min(lo + 1, 127);
    float w = pos - (float)lo;
    int il = lo - j + 1;       // in [0,2]
    int ih = hi - j + 1;
    float de[NBN][EXPR];
    #pragma unroll
    for (int bn = 0; bn < NBN; ++bn) {
        #pragma unroll
        for (int e = 0; e < EXPR; ++e)
            de[bn][e] = dloc[bn][e][il] * (1.0f - w) + dloc[bn][e][ih] * w;
    }
    float acc[NBN] = {0.f, 0.f, 0.f, 0.f, 0.f, 0.f, 0.f, 0.f};
    const float4* Gr = G4 + (size_t)r * N_SAMPLES;
    for (int f = 0; f <= j; ++f) {
        float4 g = Gr[(j - f) * STEP + o];
        #pragma unroll
        for (int bn = 0; bn < NBN; ++bn) {
            float t = de[bn][0] * g.x + de[bn][1] * g.y + de[bn][2] * g.z + de[bn][3] * g.w;
            acc[bn] = fmaf(wsm[(bn << 7) + f], t, acc[bn]);
        }
    }
    int s = j * STEP + o;
    #pragma unroll
    for (int bn = 0; bn < NBN; ++bn)
        xout[(size_t)(bn * N_RES + r) * N_SAMPLES + s] = __float2bfloat16(acc[bn]);
}

// ---------------------------------------------------------------- K6: tanh(gain*x) summed over r
__global__ __launch_bounds__(256) void k6_out(const __hip_bfloat16* __restrict__ xin,
                                              const float* __restrict__ gains,
                                              float* __restrict__ out) {
    __shared__ float gabs[N_RES];
    int bid = blockIdx.x;              // bn*128 + sc
    int sc = bid & 127, bn = bid >> 7;
    int o = threadIdx.x;
    if (o < N_RES) gabs[o] = fabsf(gains[o]);
    __syncthreads();
    int s = sc * STEP + o;
    float acc = 0.f;
    #pragma unroll 4
    for (int rr = 0; rr < N_RES; ++rr) {
        float xf = __bfloat162float(xin[(size_t)(bn * N_RES + rr) * N_SAMPLES + s]);
        acc += tanhf(xf * gabs[rr]);
    }
    out[bn * N_SAMPLES + s] = acc;
}

// ---------------------------------------------------------------- launch
extern "C" void kernel_launch(void* const* d_in, const int* in_sizes, int n_in,
                              void* d_out, int out_size, void* d_ws, size_t ws_size,
                              hipStream_t stream) {
    const float* control = (const float*)d_in[0];
    const float* defo    = (const float*)d_in[1];
    const float* router  = (const float*)d_in[2];
    const float* gains   = (const float*)d_in[3];
    const float* amp     = (const float*)d_in[4];
    const float* phase   = (const float*)d_in[5];
    const float* decay   = (const float*)d_in[6];
    const float* noise   = (const float*)d_in[7];

    float* out_summed = (float*)d_out;                     // (2,4,1,32768)
    float* out_w      = (float*)d_out + NBN * N_SAMPLES;   // (2,4,32,128) = before_upsample

    char* ws = (char*)d_ws;
    const size_t RSZ = (size_t)N_RES * EXPR * N_SAMPLES * 4;  // 16.8MB
    float4* G4      = (float4*)ws;                             // [0, RSZ)
    float*  res_raw = (float*)(ws + RSZ);                      // [RSZ, 2*RSZ)
    __hip_bfloat16* xout = (__hip_bfloat16*)(ws + RSZ);        // alias of res_raw (dead by K5)
    size_t off = 2 * RSZ;
    float* Cre = (float*)(ws + off); off += (size_t)N_RES * EXPR * KPAD * 4;
    float* Cim = (float*)(ws + off); off += (size_t)N_RES * EXPR * KPAD * 4;
    float* Dk  = (float*)(ws + off); off += (size_t)N_RES * EXPR * KPAD * 4;
    float* L2d = (float*)(ws + off); off += (size_t)N_RES * EXPR * KPAD * 4;
    float* dfr = (float*)(ws + off); off += (size_t)NBN * EXPR * CTRL * 4;
    float* inv_norm = (float*)(ws + off); off += (size_t)N_RES * EXPR * 4;

    k0_params<<<(N_RES * EXPR * KPAD + 255) / 256, 256, 0, stream>>>(amp, phase, decay, Cre, Cim, Dk, L2d);
    k4a_route<<<(NBN * N_RES * CTRL) / 256, 256, 0, stream>>>(control, router, out_w);
    k4b_dfr<<<(NBN * CTRL + 255) / 256, 256, 0, stream>>>(defo, dfr);
    k1_res<<<N_RES * EXPR * N_FRAMES, 256, 0, stream>>>(Cre, Cim, Dk, L2d, res_raw);
    k2_norm<<<N_RES * EXPR, 256, 0, stream>>>(res_raw, inv_norm);
    k3_impconv<<<N_RES * N_FRAMES, 256, 0, stream>>>(res_raw, inv_norm, noise, G4);
    k5_conv<<<N_RES * N_FRAMES, 256, 0, stream>>>(G4, out_w, dfr, xout);
    k6_out<<<NBN * N_FRAMES, 256, 0, stream>>>(xout, gains, out_summed);
}

// Round 2
// 282.454 us; speedup vs baseline: 1.7910x; 1.7910x over previous
//
#include <hip/hip_runtime.h>
#include <hip/hip_bf16.h>
#include <math.h>

#define N_SAMPLES 32768
#define STEP 256
#define N_FRAMES 128
#define N_COEFFS 257
#define KP 288            // padded per-half K (257 real coeffs + pad), mult of 32
#define CPD 16
#define N_RES 32
#define EXPR 4
#define CTRL 128
#define NBN 8             // 2*4 batch*channels
#define PI_F 3.14159265358979323846f

// ---------------------------------------------------------------- K0: per-(re,k) params
__global__ __launch_bounds__(256) void k0_params(const float* __restrict__ amp,
                                                 const float* __restrict__ phase,
                                                 const float* __restrict__ decay,
                                                 float* __restrict__ Cre, float* __restrict__ Cim,
                                                 float* __restrict__ Dk, float* __restrict__ L2d) {
    int idx = blockIdx.x * 256 + threadIdx.x;
    if (idx >= 128 * KP) return;
    int k  = idx % KP;
    int re = idx / KP;
    int r = re >> 2, e = re & 3;
    if (k >= N_COEFFS) { Cre[idx] = 0.f; Cim[idx] = 0.f; Dk[idx] = 0.5f; L2d[idx] = -1.0f; return; }
    int src = (r * N_COEFFS + k) * EXPR + e;
    float m  = fabsf(amp[src]) + 1e-12f;
    float ph = tanhf(phase[src]) * PI_F;
    float sg = 1.0f / (1.0f + expf(-decay[src]));
    float d  = 0.5f + 0.45f * sg;
    float wk = (k == 0 || k == 256) ? (1.0f / 512.0f) : (2.0f / 512.0f);
    Cre[idx] = wk * m * cosf(ph);
    Cim[idx] = wk * m * sinf(ph);
    Dk[idx]  = d;
    L2d[idx] = log2f(d);
}

// ---------------------------------------------------------------- K1: resonance GEMM
// res[o, re*128+j] = sum_k Cre*scale(k,j)*cos(2pi k o/512) - Cim*scale(k,j)*sin(...)
// A (twiddles) kept in registers via rotation recurrence; B tile generated in LDS.
template<bool IM>
__device__ __forceinline__ void gemm_half(const float* __restrict__ Cc,
                                          const float* __restrict__ dkp,
                                          const float* __restrict__ l2p,
                                          float (&acc)[4][8], float (&Bs)[32][132],
                                          int tid, int tn,
                                          const float (&c1v)[4], const float (&s1v)[4]) {
    float cr[4] = {1.f, 1.f, 1.f, 1.f};
    float ci[4] = {0.f, 0.f, 0.f, 0.f};
    int srow = tid & 31;            // staging row (k within tile)
    int j0   = (tid >> 5) << 4;     // 16 consecutive j per thread
    for (int k0s = 0; k0s < KP; k0s += 32) {
        __syncthreads();            // previous tile fully consumed
        // ---- stage B tile: B[k][j] = Cc * d^j * (d + sg)
        {
            int kf = k0s + srow;
            float c  = Cc[kf];
            float d  = dkp[kf];
            float l2 = l2p[kf];
            float sgn = (kf & 1) ? -1.f : 1.f;
            float pw = exp2f((float)j0 * l2);  // d^j0
            float m  = c * (d + sgn);          // j>=1 coefficient
            float cd = c * d;                  // j==0 coefficient
            float4 buf;
            #pragma unroll
            for (int q = 0; q < 16; ++q) {
                int j = j0 + q;
                float val = (j == 0) ? cd : m * pw;
                ((float*)&buf)[q & 3] = val;
                pw *= d;
                if ((q & 3) == 3) *(float4*)&Bs[srow][j0 + (q & ~3)] = buf;
            }
        }
        __syncthreads();
        // ---- compute
        #pragma unroll 4
        for (int kk = 0; kk < 32; ++kk) {
            float4 b0 = *(const float4*)&Bs[kk][tn << 3];
            float4 b1 = *(const float4*)&Bs[kk][(tn << 3) + 4];
            float bv[8] = {b0.x, b0.y, b0.z, b0.w, b1.x, b1.y, b1.z, b1.w};
            #pragma unroll
            for (int mi = 0; mi < 4; ++mi) {
                float a = IM ? -ci[mi] : cr[mi];
                #pragma unroll
                for (int ni = 0; ni < 8; ++ni)
                    acc[mi][ni] = fmaf(a, bv[ni], acc[mi][ni]);
                // rotate (cr,ci) by theta = 2*pi*o/512
                float t = cr[mi] * c1v[mi] - ci[mi] * s1v[mi];
                ci[mi] = fmaf(cr[mi], s1v[mi], ci[mi] * c1v[mi]);
                cr[mi] = t;
            }
        }
    }
}

__global__ __launch_bounds__(256) void k1g(const float* __restrict__ Cre, const float* __restrict__ Cim,
                                           const float* __restrict__ Dk, const float* __restrict__ L2d,
                                           float* __restrict__ res_raw) {
    __shared__ float Bs[32][132];
    int bx = blockIdx.x, re = blockIdx.y;
    int tid = threadIdx.x;
    int tm = tid & 15, tn = tid >> 4;
    int obase = bx * 64 + (tm << 2);
    float c1v[4], s1v[4];
    #pragma unroll
    for (int mi = 0; mi < 4; ++mi)
        sincosf((float)(obase + mi) * (PI_F / 256.0f), &s1v[mi], &c1v[mi]);
    float acc[4][8] = {};
    const float* cre = Cre + re * KP;
    const float* cim = Cim + re * KP;
    const float* dkp = Dk  + re * KP;
    const float* l2p = L2d + re * KP;
    gemm_half<false>(cre, dkp, l2p, acc, Bs, tid, tn, c1v, s1v);
    gemm_half<true >(cim, dkp, l2p, acc, Bs, tid, tn, c1v, s1v);
    #pragma unroll
    for (int ni = 0; ni < 8; ++ni) {
        int j = (tn << 3) + ni;
        float4 v = make_float4(acc[0][ni], acc[1][ni], acc[2][ni], acc[3][ni]);
        *(float4*)&res_raw[(size_t)re * N_SAMPLES + j * STEP + obase] = v;
    }
}

// ---------------------------------------------------------------- K2: inverse norms
__global__ __launch_bounds__(256) void k2_norm(const float* __restrict__ res_raw, float* __restrict__ inv_norm) {
    __shared__ float red[256];
    int re = blockIdx.x;
    const float* p = res_raw + (size_t)re * N_SAMPLES;
    float s = 0.f;
    for (int i = threadIdx.x; i < N_SAMPLES; i += 256) { float v = p[i]; s += v * v; }
    red[threadIdx.x] = s;
    __syncthreads();
    for (int st = 128; st > 0; st >>= 1) {
        if (threadIdx.x < st) red[threadIdx.x] += red[threadIdx.x + st];
        __syncthreads();
    }
    if (threadIdx.x == 0) inv_norm[re] = 1.0f / (sqrtf(red[0]) + 1e-8f);
}

// ---------------------------------------------------------------- K3: impulse FIR -> G (float4 over e)
__global__ __launch_bounds__(256) void k3_impconv(const float* __restrict__ res_raw,
                                                  const float* __restrict__ inv_norm,
                                                  const float* __restrict__ noise,
                                                  float4* __restrict__ G4) {
    __shared__ float st[EXPR][384];
    __shared__ float imp[128];
    int blk = blockIdx.x;
    int j = blk % N_FRAMES;
    int r = blk / N_FRAMES;
    int tid = threadIdx.x;
    for (int i = tid; i < EXPR * 384; i += 256) {
        int e = i / 384, ii = i % 384;
        int g = j * STEP - 127 + ii;
        float v = 0.f;
        if (g >= 0 && g < N_SAMPLES) v = res_raw[(size_t)(r * EXPR + e) * N_SAMPLES + g] * inv_norm[r * EXPR + e];
        st[e][ii] = v;
    }
    if (tid < 128)
        imp[tid] = (0.54f - 0.46f * cosf((2.0f * PI_F / 128.0f) * (float)tid)) * noise[tid];
    __syncthreads();
    float a0 = 0.f, a1 = 0.f, a2 = 0.f, a3 = 0.f;
    #pragma unroll 4
    for (int u = 0; u < 128; ++u) {
        float w = imp[u];
        int idx = tid + 127 - u;
        a0 = fmaf(w, st[0][idx], a0);
        a1 = fmaf(w, st[1][idx], a1);
        a2 = fmaf(w, st[2][idx], a2);
        a3 = fmaf(w, st[3][idx], a3);
    }
    G4[(size_t)r * N_SAMPLES + j * STEP + tid] = make_float4(a0, a1, a2, a3);
}

// ---------------------------------------------------------------- K4a: routed weights (= before_upsample output)
__global__ __launch_bounds__(256) void k4a_route(const float* __restrict__ control,
                                                 const float* __restrict__ router,
                                                 float* __restrict__ out_w) {
    int idx = blockIdx.x * 256 + threadIdx.x;
    int f  = idx % CTRL;
    int r  = (idx / CTRL) % N_RES;
    int bn = idx / (CTRL * N_RES);
    float s = 0.f;
    #pragma unroll
    for (int c = 0; c < CPD; ++c)
        s += control[(bn * CPD + c) * CTRL + f] * router[c * N_RES + r];
    out_w[idx] = s;
}

// ---------------------------------------------------------------- K4b: softmax over expressions per ctrl frame
__global__ __launch_bounds__(256) void k4b_dfr(const float* __restrict__ defo, float* __restrict__ d_frames) {
    int idx = blockIdx.x * 256 + threadIdx.x;
    if (idx >= NBN * CTRL) return;
    int f = idx % CTRL, bn = idx / CTRL;
    float v[EXPR]; float mx = -1e30f;
    #pragma unroll
    for (int e = 0; e < EXPR; ++e) {
        float x = defo[(bn * EXPR + e) * CTRL + f] + (e == 0 ? 1.0f : 0.0f);
        v[e] = x; mx = fmaxf(mx, x);
    }
    float sum = 0.f;
    #pragma unroll
    for (int e = 0; e < EXPR; ++e) { v[e] = expf(v[e] - mx); sum += v[e]; }
    float inv = 1.0f / sum;
    #pragma unroll
    for (int e = 0; e < EXPR; ++e) d_frames[(bn * EXPR + e) * CTRL + f] = v[e] * inv;
}

// ---------------------------------------------------------------- K5: spike-train conv + expression mix
__global__ __launch_bounds__(256) void k5_conv(const float4* __restrict__ G4,
                                               const float* __restrict__ out_w,
                                               const float* __restrict__ d_frames,
                                               __hip_bfloat16* __restrict__ xout) {
    __shared__ float wsm[NBN * CTRL];
    __shared__ float dloc[NBN][EXPR][3];
    int bid = blockIdx.x;
    int xcd = bid & 7;
    int y   = bid >> 3;
    int r   = xcd * 4 + (y & 3);
    int j   = y >> 2;
    int o = threadIdx.x;
    for (int i = o; i < NBN * CTRL; i += 256) {
        int bn = i >> 7, f = i & 127;
        wsm[i] = out_w[(bn * N_RES + r) * CTRL + f];
    }
    if (o < NBN * EXPR * 3) {
        int bn = o / 12, rem = o % 12, e = rem / 3, wch = rem % 3;
        int fr = j - 1 + wch;
        fr = fr < 0 ? 0 : (fr > 127 ? 127 : fr);
        dloc[bn][e][wch] = d_frames[(bn * EXPR + e) * CTRL + fr];
    }
    __syncthreads();
    float pos = ((float)(j * STEP + o) + 0.5f) * (1.0f / 256.0f) - 0.5f;
    pos = fminf(fmaxf(pos, 0.0f), 127.0f);
    int lo = (int)floorf(pos);
    int hi = min(lo + 1, 127);
    float w = pos - (float)lo;
    int il = lo - j + 1;
    int ih = hi - j + 1;
    float de[NBN][EXPR];
    #pragma unroll
    for (int bn = 0; bn < NBN; ++bn) {
        #pragma unroll
        for (int e = 0; e < EXPR; ++e)
            de[bn][e] = dloc[bn][e][il] * (1.0f - w) + dloc[bn][e][ih] * w;
    }
    float acc[NBN] = {0.f, 0.f, 0.f, 0.f, 0.f, 0.f, 0.f, 0.f};
    const float4* Gr = G4 + (size_t)r * N_SAMPLES;
    for (int f = 0; f <= j; ++f) {
        float4 g = Gr[(j - f) * STEP + o];
        #pragma unroll
        for (int bn = 0; bn < NBN; ++bn) {
            float t = de[bn][0] * g.x + de[bn][1] * g.y + de[bn][2] * g.z + de[bn][3] * g.w;
            acc[bn] = fmaf(wsm[(bn << 7) + f], t, acc[bn]);
        }
    }
    int s = j * STEP + o;
    #pragma unroll
    for (int bn = 0; bn < NBN; ++bn)
        xout[(size_t)(bn * N_RES + r) * N_SAMPLES + s] = __float2bfloat16(acc[bn]);
}

// ---------------------------------------------------------------- K6: tanh(gain*x) summed over r
__global__ __launch_bounds__(256) void k6_out(const __hip_bfloat16* __restrict__ xin,
                                              const float* __restrict__ gains,
                                              float* __restrict__ out) {
    __shared__ float gabs[N_RES];
    int bid = blockIdx.x;
    int sc = bid & 127, bn = bid >> 7;
    int o = threadIdx.x;
    if (o < N_RES) gabs[o] = fabsf(gains[o]);
    __syncthreads();
    int s = sc * STEP + o;
    float acc = 0.f;
    #pragma unroll 4
    for (int rr = 0; rr < N_RES; ++rr) {
        float xf = __bfloat162float(xin[(size_t)(bn * N_RES + rr) * N_SAMPLES + s]);
        acc += tanhf(xf * gabs[rr]);
    }
    out[bn * N_SAMPLES + s] = acc;
}

// ---------------------------------------------------------------- launch
extern "C" void kernel_launch(void* const* d_in, const int* in_sizes, int n_in,
                              void* d_out, int out_size, void* d_ws, size_t ws_size,
                              hipStream_t stream) {
    const float* control = (const float*)d_in[0];
    const float* defo    = (const float*)d_in[1];
    const float* router  = (const float*)d_in[2];
    const float* gains   = (const float*)d_in[3];
    const float* amp     = (const float*)d_in[4];
    const float* phase   = (const float*)d_in[5];
    const float* decay   = (const float*)d_in[6];
    const float* noise   = (const float*)d_in[7];

    float* out_summed = (float*)d_out;
    float* out_w      = (float*)d_out + NBN * N_SAMPLES;

    char* ws = (char*)d_ws;
    const size_t RSZ = (size_t)N_RES * EXPR * N_SAMPLES * 4;   // 16.8MB
    float4* G4      = (float4*)ws;                              // [0, RSZ)
    float*  res_raw = (float*)(ws + RSZ);                       // [RSZ, 2RSZ)
    __hip_bfloat16* xout = (__hip_bfloat16*)(ws + RSZ);         // alias (res_raw dead after k3)
    size_t off = 2 * RSZ;
    float* Cre = (float*)(ws + off); off += (size_t)128 * KP * 4;
    float* Cim = (float*)(ws + off); off += (size_t)128 * KP * 4;
    float* Dk  = (float*)(ws + off); off += (size_t)128 * KP * 4;
    float* L2d = (float*)(ws + off); off += (size_t)128 * KP * 4;
    float* dfr = (float*)(ws + off); off += (size_t)NBN * EXPR * CTRL * 4;
    float* inv_norm = (float*)(ws + off); off += (size_t)N_RES * EXPR * 4;

    k0_params<<<(128 * KP + 255) / 256, 256, 0, stream>>>(amp, phase, decay, Cre, Cim, Dk, L2d);
    k4a_route<<<(NBN * N_RES * CTRL) / 256, 256, 0, stream>>>(control, router, out_w);
    k4b_dfr<<<(NBN * CTRL + 255) / 256, 256, 0, stream>>>(defo, dfr);
    k1g<<<dim3(4, 128), 256, 0, stream>>>(Cre, Cim, Dk, L2d, res_raw);
    k2_norm<<<N_RES * EXPR, 256, 0, stream>>>(res_raw, inv_norm);
    k3_impconv<<<N_RES * N_FRAMES, 256, 0, stream>>>(res_raw, inv_norm, noise, G4);
    k5_conv<<<N_RES * N_FRAMES, 256, 0, stream>>>(G4, out_w, dfr, xout);
    k6_out<<<NBN * N_FRAMES, 256, 0, stream>>>(xout, gains, out_summed);
}

// Round 3
// 241.120 us; speedup vs baseline: 2.0980x; 1.1714x over previous
//
#include <hip/hip_runtime.h>
#include <hip/hip_bf16.h>
#include <math.h>

#define N_SAMPLES 32768
#define STEP 256
#define N_FRAMES 128
#define N_COEFFS 257
#define KP 288            // padded per-half K (257 real coeffs + pad), mult of 32
#define CPD 16
#define N_RES 32
#define EXPR 4
#define CTRL 128
#define NBN 8             // 2*4 batch*channels
#define PI_F 3.14159265358979323846f

// ---------------------------------------------------------------- K0: per-(re,k) params
__global__ __launch_bounds__(256) void k0_params(const float* __restrict__ amp,
                                                 const float* __restrict__ phase,
                                                 const float* __restrict__ decay,
                                                 float* __restrict__ Cre, float* __restrict__ Cim,
                                                 float* __restrict__ Dk, float* __restrict__ L2d) {
    int idx = blockIdx.x * 256 + threadIdx.x;
    if (idx >= 128 * KP) return;
    int k  = idx % KP;
    int re = idx / KP;
    int r = re >> 2, e = re & 3;
    if (k >= N_COEFFS) { Cre[idx] = 0.f; Cim[idx] = 0.f; Dk[idx] = 0.5f; L2d[idx] = -1.0f; return; }
    int src = (r * N_COEFFS + k) * EXPR + e;
    float m  = fabsf(amp[src]) + 1e-12f;
    float ph = tanhf(phase[src]) * PI_F;
    float sg = 1.0f / (1.0f + expf(-decay[src]));
    float d  = 0.5f + 0.45f * sg;
    float wk = (k == 0 || k == 256) ? (1.0f / 512.0f) : (2.0f / 512.0f);
    Cre[idx] = wk * m * cosf(ph);
    Cim[idx] = wk * m * sinf(ph);
    Dk[idx]  = d;
    L2d[idx] = log2f(d);
}

// ---------------------------------------------------------------- K1: resonance GEMM
template<bool IM>
__device__ __forceinline__ void gemm_half(const float* __restrict__ Cc,
                                          const float* __restrict__ dkp,
                                          const float* __restrict__ l2p,
                                          float (&acc)[4][8], float (&Bs)[32][132],
                                          int tid, int tn,
                                          const float (&c1v)[4], const float (&s1v)[4]) {
    float cr[4] = {1.f, 1.f, 1.f, 1.f};
    float ci[4] = {0.f, 0.f, 0.f, 0.f};
    int srow = tid & 31;
    int j0   = (tid >> 5) << 4;
    for (int k0s = 0; k0s < KP; k0s += 32) {
        __syncthreads();
        {
            int kf = k0s + srow;
            float c  = Cc[kf];
            float d  = dkp[kf];
            float l2 = l2p[kf];
            float sgn = (kf & 1) ? -1.f : 1.f;
            float pw = exp2f((float)j0 * l2);
            float m  = c * (d + sgn);
            float cd = c * d;
            float4 buf;
            #pragma unroll
            for (int q = 0; q < 16; ++q) {
                int j = j0 + q;
                float val = (j == 0) ? cd : m * pw;
                ((float*)&buf)[q & 3] = val;
                pw *= d;
                if ((q & 3) == 3) *(float4*)&Bs[srow][j0 + (q & ~3)] = buf;
            }
        }
        __syncthreads();
        #pragma unroll 4
        for (int kk = 0; kk < 32; ++kk) {
            float4 b0 = *(const float4*)&Bs[kk][tn << 3];
            float4 b1 = *(const float4*)&Bs[kk][(tn << 3) + 4];
            float bv[8] = {b0.x, b0.y, b0.z, b0.w, b1.x, b1.y, b1.z, b1.w};
            #pragma unroll
            for (int mi = 0; mi < 4; ++mi) {
                float a = IM ? -ci[mi] : cr[mi];
                #pragma unroll
                for (int ni = 0; ni < 8; ++ni)
                    acc[mi][ni] = fmaf(a, bv[ni], acc[mi][ni]);
                float t = cr[mi] * c1v[mi] - ci[mi] * s1v[mi];
                ci[mi] = fmaf(cr[mi], s1v[mi], ci[mi] * c1v[mi]);
                cr[mi] = t;
            }
        }
    }
}

__global__ __launch_bounds__(256) void k1g(const float* __restrict__ Cre, const float* __restrict__ Cim,
                                           const float* __restrict__ Dk, const float* __restrict__ L2d,
                                           float* __restrict__ res_raw) {
    __shared__ float Bs[32][132];
    int bx = blockIdx.x, re = blockIdx.y;
    int tid = threadIdx.x;
    int tm = tid & 15, tn = tid >> 4;
    int obase = bx * 64 + (tm << 2);
    float c1v[4], s1v[4];
    #pragma unroll
    for (int mi = 0; mi < 4; ++mi)
        sincosf((float)(obase + mi) * (PI_F / 256.0f), &s1v[mi], &c1v[mi]);
    float acc[4][8] = {};
    const float* cre = Cre + re * KP;
    const float* cim = Cim + re * KP;
    const float* dkp = Dk  + re * KP;
    const float* l2p = L2d + re * KP;
    gemm_half<false>(cre, dkp, l2p, acc, Bs, tid, tn, c1v, s1v);
    gemm_half<true >(cim, dkp, l2p, acc, Bs, tid, tn, c1v, s1v);
    #pragma unroll
    for (int ni = 0; ni < 8; ++ni) {
        int j = (tn << 3) + ni;
        float4 v = make_float4(acc[0][ni], acc[1][ni], acc[2][ni], acc[3][ni]);
        *(float4*)&res_raw[(size_t)re * N_SAMPLES + j * STEP + obase] = v;
    }
}

// ---------------------------------------------------------------- K2: inverse norms
__global__ __launch_bounds__(256) void k2_norm(const float* __restrict__ res_raw, float* __restrict__ inv_norm) {
    __shared__ float red[256];
    int re = blockIdx.x;
    const float* p = res_raw + (size_t)re * N_SAMPLES;
    float s = 0.f;
    for (int i = threadIdx.x; i < N_SAMPLES; i += 256) { float v = p[i]; s += v * v; }
    red[threadIdx.x] = s;
    __syncthreads();
    for (int st = 128; st > 0; st >>= 1) {
        if (threadIdx.x < st) red[threadIdx.x] += red[threadIdx.x + st];
        __syncthreads();
    }
    if (threadIdx.x == 0) inv_norm[re] = 1.0f / (sqrtf(red[0]) + 1e-8f);
}

// ---------------------------------------------------------------- K3: impulse FIR -> G (float4 over e)
__global__ __launch_bounds__(256) void k3_impconv(const float* __restrict__ res_raw,
                                                  const float* __restrict__ inv_norm,
                                                  const float* __restrict__ noise,
                                                  float4* __restrict__ G4) {
    __shared__ float st[EXPR][384];
    __shared__ float imp[128];
    int blk = blockIdx.x;
    int j = blk % N_FRAMES;
    int r = blk / N_FRAMES;
    int tid = threadIdx.x;
    for (int i = tid; i < EXPR * 384; i += 256) {
        int e = i / 384, ii = i % 384;
        int g = j * STEP - 127 + ii;
        float v = 0.f;
        if (g >= 0 && g < N_SAMPLES) v = res_raw[(size_t)(r * EXPR + e) * N_SAMPLES + g] * inv_norm[r * EXPR + e];
        st[e][ii] = v;
    }
    if (tid < 128)
        imp[tid] = (0.54f - 0.46f * cosf((2.0f * PI_F / 128.0f) * (float)tid)) * noise[tid];
    __syncthreads();
    float a0 = 0.f, a1 = 0.f, a2 = 0.f, a3 = 0.f;
    #pragma unroll 4
    for (int u = 0; u < 128; ++u) {
        float w = imp[u];
        int idx = tid + 127 - u;
        a0 = fmaf(w, st[0][idx], a0);
        a1 = fmaf(w, st[1][idx], a1);
        a2 = fmaf(w, st[2][idx], a2);
        a3 = fmaf(w, st[3][idx], a3);
    }
    G4[(size_t)r * N_SAMPLES + j * STEP + tid] = make_float4(a0, a1, a2, a3);
}

// ---------------------------------------------------------------- K4a: routed weights (= before_upsample output)
__global__ __launch_bounds__(256) void k4a_route(const float* __restrict__ control,
                                                 const float* __restrict__ router,
                                                 float* __restrict__ out_w) {
    int idx = blockIdx.x * 256 + threadIdx.x;
    int f  = idx % CTRL;
    int r  = (idx / CTRL) % N_RES;
    int bn = idx / (CTRL * N_RES);
    float s = 0.f;
    #pragma unroll
    for (int c = 0; c < CPD; ++c)
        s += control[(bn * CPD + c) * CTRL + f] * router[c * N_RES + r];
    out_w[idx] = s;
}

// ---------------------------------------------------------------- K4b: softmax over expressions per ctrl frame
__global__ __launch_bounds__(256) void k4b_dfr(const float* __restrict__ defo, float* __restrict__ d_frames) {
    int idx = blockIdx.x * 256 + threadIdx.x;
    if (idx >= NBN * CTRL) return;
    int f = idx % CTRL, bn = idx / CTRL;
    float v[EXPR]; float mx = -1e30f;
    #pragma unroll
    for (int e = 0; e < EXPR; ++e) {
        float x = defo[(bn * EXPR + e) * CTRL + f] + (e == 0 ? 1.0f : 0.0f);
        v[e] = x; mx = fmaxf(mx, x);
    }
    float sum = 0.f;
    #pragma unroll
    for (int e = 0; e < EXPR; ++e) { v[e] = expf(v[e] - mx); sum += v[e]; }
    float inv = 1.0f / sum;
    #pragma unroll
    for (int e = 0; e < EXPR; ++e) d_frames[(bn * EXPR + e) * CTRL + f] = v[e] * inv;
}

// ---------------------------------------------------------------- K5 v3: duo-blocked spike conv, de hoisted to epilogue
struct W8 { float4 lo, hi; };

__device__ __forceinline__ W8 ldw(const float (*wT)[8], int f) {
    W8 w;
    w.lo = *(const float4*)&wT[f][0];
    w.hi = *(const float4*)&wT[f][4];
    return w;
}

__device__ __forceinline__ void fma8(float4 (&acc)[NBN], const W8& w, const float4& g) {
    const float wv[NBN] = {w.lo.x, w.lo.y, w.lo.z, w.lo.w, w.hi.x, w.hi.y, w.hi.z, w.hi.w};
    #pragma unroll
    for (int bn = 0; bn < NBN; ++bn) {
        acc[bn].x = fmaf(wv[bn], g.x, acc[bn].x);
        acc[bn].y = fmaf(wv[bn], g.y, acc[bn].y);
        acc[bn].z = fmaf(wv[bn], g.z, acc[bn].z);
        acc[bn].w = fmaf(wv[bn], g.w, acc[bn].w);
    }
}

__device__ __forceinline__ void epilogue(const float4 (&acc)[NBN], int j, int o, int r,
                                         const float* __restrict__ dfr,
                                         __hip_bfloat16* __restrict__ xout) {
    int s = j * STEP + o;
    float pos = ((float)s + 0.5f) * (1.0f / 256.0f) - 0.5f;
    pos = fminf(fmaxf(pos, 0.0f), 127.0f);
    int lo = (int)floorf(pos);
    int hi = min(lo + 1, 127);
    float w = pos - (float)lo;
    #pragma unroll
    for (int bn = 0; bn < NBN; ++bn) {
        float out = 0.f;
        #pragma unroll
        for (int e = 0; e < EXPR; ++e) {
            const float* dptr = dfr + (bn * EXPR + e) * CTRL;
            float de = dptr[lo] * (1.0f - w) + dptr[hi] * w;
            out = fmaf(de, ((const float*)&acc[bn])[e], out);
        }
        xout[(size_t)(bn * N_RES + r) * N_SAMPLES + s] = __float2bfloat16(out);
    }
}

__device__ __forceinline__ void run_duo(int j1, int o, int r,
                                        const float4* __restrict__ Gr,
                                        const float (*wT)[8],
                                        const float* __restrict__ dfr,
                                        __hip_bfloat16* __restrict__ xout) {
    float4 acc0[NBN] = {};   // j = j1-1
    float4 acc1[NBN] = {};   // j = j1
    W8 wA = ldw(wT, j1);     // row f1 = j1 - k, starts at j1
    W8 wB;
    int k = 0;
    for (; k + 1 < j1; k += 2) {
        float4 g0 = Gr[k * STEP + o];
        wB = ldw(wT, j1 - k - 1);
        fma8(acc1, wA, g0);
        fma8(acc0, wB, g0);
        float4 g1 = Gr[(k + 1) * STEP + o];
        wA = ldw(wT, j1 - k - 2);
        fma8(acc1, wB, g1);
        fma8(acc0, wA, g1);
    }
    if (k < j1) {            // one more full iteration (f0 = 0)
        float4 g = Gr[k * STEP + o];
        wB = ldw(wT, j1 - k - 1);
        fma8(acc1, wA, g);
        fma8(acc0, wB, g);
        k++;
    }
    {                        // k == j1: f1 = 0 term for acc1 only
        float4 g = Gr[j1 * STEP + o];
        W8 w0 = ldw(wT, 0);
        fma8(acc1, w0, g);
    }
    epilogue(acc0, j1 - 1, o, r, dfr, xout);
    epilogue(acc1, j1,     o, r, dfr, xout);
}

__global__ __launch_bounds__(256) void k5_conv(const float4* __restrict__ G4,
                                               const float* __restrict__ out_w,
                                               const float* __restrict__ dfr,
                                               __hip_bfloat16* __restrict__ xout) {
    __shared__ __align__(16) float wT[CTRL][8];   // wT[f][bn]
    int bid = blockIdx.x;                          // 1024 blocks
    int xcd = bid & 7;
    int y   = bid >> 3;                            // 0..127
    int r   = xcd * 4 + (y & 3);
    int dp  = y >> 2;                              // 0..31 duo-pair index
    int o = threadIdx.x;
    for (int i = o; i < CTRL * NBN; i += 256) {
        int f = i >> 3, bn = i & 7;
        wT[f][bn] = out_w[(bn * N_RES + r) * CTRL + f];
    }
    __syncthreads();
    const float4* Gr = G4 + (size_t)r * N_SAMPLES;
    run_duo(2 * dp + 1,  o, r, Gr, wT, dfr, xout);   // j in {2dp, 2dp+1}
    run_duo(127 - 2 * dp, o, r, Gr, wT, dfr, xout);  // j in {126-2dp, 127-2dp}
}

// ---------------------------------------------------------------- K6: tanh(gain*x) summed over r
__global__ __launch_bounds__(256) void k6_out(const __hip_bfloat16* __restrict__ xin,
                                              const float* __restrict__ gains,
                                              float* __restrict__ out) {
    __shared__ float gabs[N_RES];
    int bid = blockIdx.x;
    int sc = bid & 127, bn = bid >> 7;
    int o = threadIdx.x;
    if (o < N_RES) gabs[o] = fabsf(gains[o]);
    __syncthreads();
    int s = sc * STEP + o;
    float acc = 0.f;
    #pragma unroll 4
    for (int rr = 0; rr < N_RES; ++rr) {
        float xf = __bfloat162float(xin[(size_t)(bn * N_RES + rr) * N_SAMPLES + s]);
        acc += tanhf(xf * gabs[rr]);
    }
    out[bn * N_SAMPLES + s] = acc;
}

// ---------------------------------------------------------------- launch
extern "C" void kernel_launch(void* const* d_in, const int* in_sizes, int n_in,
                              void* d_out, int out_size, void* d_ws, size_t ws_size,
                              hipStream_t stream) {
    const float* control = (const float*)d_in[0];
    const float* defo    = (const float*)d_in[1];
    const float* router  = (const float*)d_in[2];
    const float* gains   = (const float*)d_in[3];
    const float* amp     = (const float*)d_in[4];
    const float* phase   = (const float*)d_in[5];
    const float* decay   = (const float*)d_in[6];
    const float* noise   = (const float*)d_in[7];

    float* out_summed = (float*)d_out;
    float* out_w      = (float*)d_out + NBN * N_SAMPLES;

    char* ws = (char*)d_ws;
    const size_t RSZ = (size_t)N_RES * EXPR * N_SAMPLES * 4;   // 16.8MB
    float4* G4      = (float4*)ws;                              // [0, RSZ)
    float*  res_raw = (float*)(ws + RSZ);                       // [RSZ, 2RSZ)
    __hip_bfloat16* xout = (__hip_bfloat16*)(ws + RSZ);         // alias (res_raw dead after k3)
    size_t off = 2 * RSZ;
    float* Cre = (float*)(ws + off); off += (size_t)128 * KP * 4;
    float* Cim = (float*)(ws + off); off += (size_t)128 * KP * 4;
    float* Dk  = (float*)(ws + off); off += (size_t)128 * KP * 4;
    float* L2d = (float*)(ws + off); off += (size_t)128 * KP * 4;
    float* dfr = (float*)(ws + off); off += (size_t)NBN * EXPR * CTRL * 4;
    float* inv_norm = (float*)(ws + off); off += (size_t)N_RES * EXPR * 4;

    k0_params<<<(128 * KP + 255) / 256, 256, 0, stream>>>(amp, phase, decay, Cre, Cim, Dk, L2d);
    k4a_route<<<(NBN * N_RES * CTRL) / 256, 256, 0, stream>>>(control, router, out_w);
    k4b_dfr<<<(NBN * CTRL + 255) / 256, 256, 0, stream>>>(defo, dfr);
    k1g<<<dim3(4, 128), 256, 0, stream>>>(Cre, Cim, Dk, L2d, res_raw);
    k2_norm<<<N_RES * EXPR, 256, 0, stream>>>(res_raw, inv_norm);
    k3_impconv<<<N_RES * N_FRAMES, 256, 0, stream>>>(res_raw, inv_norm, noise, G4);
    k5_conv<<<1024, 256, 0, stream>>>(G4, out_w, dfr, xout);
    k6_out<<<NBN * N_FRAMES, 256, 0, stream>>>(xout, gains, out_summed);
}

// Round 4
// 166.917 us; speedup vs baseline: 3.0307x; 1.4446x over previous
//
#include <hip/hip_runtime.h>
#include <hip/hip_bf16.h>
#include <math.h>

#define N_SAMPLES 32768
#define STEP 256
#define N_FRAMES 128
#define N_COEFFS 257
#define KT 576            // stacked K: 288 (cos/Cre) + 288 (sin/-Cim)
#define NKS 18            // K-steps of 32
#define CPD 16
#define N_RES 32
#define EXPR 4
#define CTRL 128
#define NBN 8
#define PI_F 3.14159265358979323846f

typedef __attribute__((ext_vector_type(8))) short bf16x8;
typedef __attribute__((ext_vector_type(4))) float f32x4;

// ---------------------------------------------------------------- K0: per-(re,k) scalar params (P, Z, L2)
__global__ __launch_bounds__(256) void k0_params(const float* __restrict__ amp,
                                                 const float* __restrict__ phase,
                                                 const float* __restrict__ decay,
                                                 float* __restrict__ Pa, float* __restrict__ Za,
                                                 float* __restrict__ L2a) {
    int idx = blockIdx.x * 256 + threadIdx.x;     // 128*576 = 73728
    if (idx >= 128 * KT) return;
    int k  = idx % KT;
    int re = idx / KT;
    int r = re >> 2, e = re & 3;
    int kk = (k < 288) ? k : k - 288;
    float P = 0.f, Z = 0.f, L2v = 0.f;
    if (kk < N_COEFFS) {
        int src = (r * N_COEFFS + kk) * EXPR + e;
        float m  = fabsf(amp[src]) + 1e-12f;
        float ph = tanhf(phase[src]) * PI_F;
        float sg = 1.0f / (1.0f + expf(-decay[src]));
        float d  = 0.5f + 0.45f * sg;
        float wk = (kk == 0 || kk == 256) ? (1.0f / 512.0f) : (2.0f / 512.0f);
        float c  = (k < 288) ? (wk * m * cosf(ph)) : (-wk * m * sinf(ph));
        float sgn = (kk & 1) ? -1.f : 1.f;
        P = c * (d + sgn);        // coefficient for j>=1 (times d^j)
        Z = c * d;                // j==0 value
        L2v = log2f(d);
    }
    Pa[idx] = P; Za[idx] = Z; L2a[idx] = L2v;
}

// ---------------------------------------------------------------- K0a: A (twiddles) in MFMA frag order, bf16
// storage f = ((ot*18 + s)*64 + l)*8 + e ; value A[o = ot*16+(l&15)][k = s*32 + (e>>2)*16 + ((l>>4)&3)*4 + (e&3)]
__global__ __launch_bounds__(256) void k0a_afrag(__hip_bfloat16* __restrict__ Afrag) {
    int f = blockIdx.x * 256 + threadIdx.x;       // 16*18*64*8 = 147456
    int e = f & 7;
    int l = (f >> 3) & 63;
    int s = (f >> 9) % NKS;
    int ot = f / (NKS * 512);
    int o = ot * 16 + (l & 15);
    int k = s * 32 + ((e >> 2) << 4) + (((l >> 4) & 3) << 2) + (e & 3);
    float v;
    if (k < 288) v = cosf((float)((k * o) & 511) * (2.0f * PI_F / 512.0f));
    else { int kk = k - 288; v = sinf((float)((kk * o) & 511) * (2.0f * PI_F / 512.0f)); }
    Afrag[f] = __float2bfloat16(v);
}

// ---------------------------------------------------------------- K0b: B matrix bf16, frag-order rows
// storage f = ((re*18 + s)*128 + j)*32 + p, p = g*8+e ; B[k][j], k = s*32 + (e>>2)*16 + g*4 + (e&3)
__global__ __launch_bounds__(256) void k0b_bgen(const float* __restrict__ Pa, const float* __restrict__ Za,
                                                const float* __restrict__ L2a,
                                                __hip_bfloat16* __restrict__ Bbf) {
    int f = blockIdx.x * 256 + threadIdx.x;       // 128*18*128*32 = 9437184
    int p = f & 31;
    int j = (f >> 5) & 127;
    int rs = f >> 12;
    int s = rs % NKS;
    int re = rs / NKS;
    int g = p >> 3, e = p & 7;
    int k = s * 32 + ((e >> 2) << 4) + (g << 2) + (e & 3);
    int ix = re * KT + k;
    float val = (j == 0) ? Za[ix] : Pa[ix] * exp2f((float)j * L2a[ix]);
    Bbf[f] = __float2bfloat16(val);
}

// ---------------------------------------------------------------- K1m: MFMA resonance GEMM (256o x 16384n, K=576)
__global__ __launch_bounds__(256) void k1m(const short* __restrict__ Afrag,
                                           const short* __restrict__ Bbf,
                                           float* __restrict__ res_raw,
                                           float* __restrict__ normp) {
    __shared__ short Bs[2][2048];     // double-buffered 64j x 32k bf16 tile (4KB each)
    __shared__ float red[256];
    int tid = threadIdx.x;
    int l = tid & 63, w = tid >> 6;
    // XCD-swizzle: colocate each re's 8 blocks on one XCD (L2-residency for Bbf slice)
    int bid = blockIdx.x;             // 1024
    int x = bid & 7, m = bid >> 3;
    int re = x * 16 + (m >> 3);
    int sub = m & 7;
    int bx = sub >> 1, jb = sub & 1;

    int otile = bx * 4 + w;
    bf16x8 af[NKS];
    #pragma unroll
    for (int s = 0; s < NKS; ++s)
        af[s] = *(const bf16x8*)(Afrag + ((size_t)(otile * NKS + s) * 64 + l) * 8);

    f32x4 acc[4] = {{0.f,0.f,0.f,0.f},{0.f,0.f,0.f,0.f},{0.f,0.f,0.f,0.f},{0.f,0.f,0.f,0.f}};
    const short* Bsrc = Bbf + (size_t)re * (NKS * 4096) + jb * 2048;

    // prologue: stage k-step 0 into buf 0
    __builtin_amdgcn_global_load_lds(
        (__attribute__((address_space(1))) const void*)(Bsrc + tid * 8),
        (__attribute__((address_space(3))) void*)(&Bs[0][tid * 8]), 16, 0, 0);

    int boff = (l & 15) * 32 + (l >> 4) * 8;
    int cur = 0;
    #pragma unroll
    for (int s = 0; s < NKS; ++s) {
        __syncthreads();              // stage(s) complete; prev buf's reads done
        if (s < NKS - 1)
            __builtin_amdgcn_global_load_lds(
                (__attribute__((address_space(1))) const void*)(Bsrc + (s + 1) * 4096 + tid * 8),
                (__attribute__((address_space(3))) void*)(&Bs[cur ^ 1][tid * 8]), 16, 0, 0);
        const short* bp = &Bs[cur][0];
        #pragma unroll
        for (int jt = 0; jt < 4; ++jt) {
            bf16x8 bf = *(const bf16x8*)(bp + jt * 512 + boff);
            acc[jt] = __builtin_amdgcn_mfma_f32_16x16x32_bf16(af[s], bf, acc[jt], 0, 0, 0);
        }
        cur ^= 1;
    }

    // epilogue: write res + norm^2 partial
    int o0 = otile * 16 + ((l >> 4) & 3) * 4;
    int jbase = jb * 64 + (l & 15);
    float s2 = 0.f;
    #pragma unroll
    for (int jt = 0; jt < 4; ++jt) {
        int j = jbase + jt * 16;
        float4 v = make_float4(acc[jt][0], acc[jt][1], acc[jt][2], acc[jt][3]);
        s2 += v.x * v.x + v.y * v.y + v.z * v.z + v.w * v.w;
        *(float4*)&res_raw[(size_t)re * N_SAMPLES + j * STEP + o0] = v;
    }
    red[tid] = s2;
    __syncthreads();
    for (int st = 128; st > 0; st >>= 1) {
        if (tid < st) red[tid] += red[tid + st];
        __syncthreads();
    }
    if (tid == 0) normp[re * 8 + bx * 2 + jb] = red[0];
}

// ---------------------------------------------------------------- K2: finalize inverse norms
__global__ void k2_fin(const float* __restrict__ normp, float* __restrict__ inv_norm) {
    int t = threadIdx.x;
    if (t >= 128) return;
    float s = 0.f;
    #pragma unroll
    for (int i = 0; i < 8; ++i) s += normp[t * 8 + i];
    inv_norm[t] = 1.0f / (sqrtf(s) + 1e-8f);
}

// ---------------------------------------------------------------- K3: impulse FIR -> G (float4 over e)
__global__ __launch_bounds__(256) void k3_impconv(const float* __restrict__ res_raw,
                                                  const float* __restrict__ inv_norm,
                                                  const float* __restrict__ noise,
                                                  float4* __restrict__ G4) {
    __shared__ float st[EXPR][384];
    __shared__ float imp[128];
    int blk = blockIdx.x;
    int j = blk % N_FRAMES;
    int r = blk / N_FRAMES;
    int tid = threadIdx.x;
    for (int i = tid; i < EXPR * 384; i += 256) {
        int e = i / 384, ii = i % 384;
        int g = j * STEP - 127 + ii;
        float v = 0.f;
        if (g >= 0 && g < N_SAMPLES) v = res_raw[(size_t)(r * EXPR + e) * N_SAMPLES + g] * inv_norm[r * EXPR + e];
        st[e][ii] = v;
    }
    if (tid < 128)
        imp[tid] = (0.54f - 0.46f * cosf((2.0f * PI_F / 128.0f) * (float)tid)) * noise[tid];
    __syncthreads();
    float a0 = 0.f, a1 = 0.f, a2 = 0.f, a3 = 0.f;
    #pragma unroll 4
    for (int u = 0; u < 128; ++u) {
        float w = imp[u];
        int idx = tid + 127 - u;
        a0 = fmaf(w, st[0][idx], a0);
        a1 = fmaf(w, st[1][idx], a1);
        a2 = fmaf(w, st[2][idx], a2);
        a3 = fmaf(w, st[3][idx], a3);
    }
    G4[(size_t)r * N_SAMPLES + j * STEP + tid] = make_float4(a0, a1, a2, a3);
}

// ---------------------------------------------------------------- K4a: routed weights (= before_upsample output)
__global__ __launch_bounds__(256) void k4a_route(const float* __restrict__ control,
                                                 const float* __restrict__ router,
                                                 float* __restrict__ out_w) {
    int idx = blockIdx.x * 256 + threadIdx.x;
    int f  = idx % CTRL;
    int r  = (idx / CTRL) % N_RES;
    int bn = idx / (CTRL * N_RES);
    float s = 0.f;
    #pragma unroll
    for (int c = 0; c < CPD; ++c)
        s += control[(bn * CPD + c) * CTRL + f] * router[c * N_RES + r];
    out_w[idx] = s;
}

// ---------------------------------------------------------------- K4b: softmax over expressions per ctrl frame
__global__ __launch_bounds__(256) void k4b_dfr(const float* __restrict__ defo, float* __restrict__ d_frames) {
    int idx = blockIdx.x * 256 + threadIdx.x;
    if (idx >= NBN * CTRL) return;
    int f = idx % CTRL, bn = idx / CTRL;
    float v[EXPR]; float mx = -1e30f;
    #pragma unroll
    for (int e = 0; e < EXPR; ++e) {
        float xv = defo[(bn * EXPR + e) * CTRL + f] + (e == 0 ? 1.0f : 0.0f);
        v[e] = xv; mx = fmaxf(mx, xv);
    }
    float sum = 0.f;
    #pragma unroll
    for (int e = 0; e < EXPR; ++e) { v[e] = expf(v[e] - mx); sum += v[e]; }
    float inv = 1.0f / sum;
    #pragma unroll
    for (int e = 0; e < EXPR; ++e) d_frames[(bn * EXPR + e) * CTRL + f] = v[e] * inv;
}

// ---------------------------------------------------------------- K5: duo-blocked spike conv, de hoisted to epilogue
struct W8 { float4 lo, hi; };

__device__ __forceinline__ W8 ldw(const float (*wT)[8], int f) {
    W8 w;
    w.lo = *(const float4*)&wT[f][0];
    w.hi = *(const float4*)&wT[f][4];
    return w;
}

__device__ __forceinline__ void fma8(float4 (&acc)[NBN], const W8& w, const float4& g) {
    const float wv[NBN] = {w.lo.x, w.lo.y, w.lo.z, w.lo.w, w.hi.x, w.hi.y, w.hi.z, w.hi.w};
    #pragma unroll
    for (int bn = 0; bn < NBN; ++bn) {
        acc[bn].x = fmaf(wv[bn], g.x, acc[bn].x);
        acc[bn].y = fmaf(wv[bn], g.y, acc[bn].y);
        acc[bn].z = fmaf(wv[bn], g.z, acc[bn].z);
        acc[bn].w = fmaf(wv[bn], g.w, acc[bn].w);
    }
}

__device__ __forceinline__ void epilogue(const float4 (&acc)[NBN], int j, int o, int r,
                                         const float* __restrict__ dfr,
                                         __hip_bfloat16* __restrict__ xout) {
    int s = j * STEP + o;
    float pos = ((float)s + 0.5f) * (1.0f / 256.0f) - 0.5f;
    pos = fminf(fmaxf(pos, 0.0f), 127.0f);
    int lo = (int)floorf(pos);
    int hi = min(lo + 1, 127);
    float w = pos - (float)lo;
    #pragma unroll
    for (int bn = 0; bn < NBN; ++bn) {
        float out = 0.f;
        #pragma unroll
        for (int e = 0; e < EXPR; ++e) {
            const float* dptr = dfr + (bn * EXPR + e) * CTRL;
            float de = dptr[lo] * (1.0f - w) + dptr[hi] * w;
            out = fmaf(de, ((const float*)&acc[bn])[e], out);
        }
        xout[(size_t)(bn * N_RES + r) * N_SAMPLES + s] = __float2bfloat16(out);
    }
}

__device__ __forceinline__ void run_duo(int j1, int o, int r,
                                        const float4* __restrict__ Gr,
                                        const float (*wT)[8],
                                        const float* __restrict__ dfr,
                                        __hip_bfloat16* __restrict__ xout) {
    float4 acc0[NBN] = {};
    float4 acc1[NBN] = {};
    W8 wA = ldw(wT, j1);
    W8 wB;
    int k = 0;
    for (; k + 1 < j1; k += 2) {
        float4 g0 = Gr[k * STEP + o];
        wB = ldw(wT, j1 - k - 1);
        fma8(acc1, wA, g0);
        fma8(acc0, wB, g0);
        float4 g1 = Gr[(k + 1) * STEP + o];
        wA = ldw(wT, j1 - k - 2);
        fma8(acc1, wB, g1);
        fma8(acc0, wA, g1);
    }
    if (k < j1) {
        float4 g = Gr[k * STEP + o];
        wB = ldw(wT, j1 - k - 1);
        fma8(acc1, wA, g);
        fma8(acc0, wB, g);
        k++;
    }
    {
        float4 g = Gr[j1 * STEP + o];
        W8 w0 = ldw(wT, 0);
        fma8(acc1, w0, g);
    }
    epilogue(acc0, j1 - 1, o, r, dfr, xout);
    epilogue(acc1, j1,     o, r, dfr, xout);
}

__global__ __launch_bounds__(256) void k5_conv(const float4* __restrict__ G4,
                                               const float* __restrict__ out_w,
                                               const float* __restrict__ dfr,
                                               __hip_bfloat16* __restrict__ xout) {
    __shared__ __align__(16) float wT[CTRL][8];
    int bid = blockIdx.x;
    int xcd = bid & 7;
    int y   = bid >> 3;
    int r   = xcd * 4 + (y & 3);
    int dp  = y >> 2;
    int o = threadIdx.x;
    for (int i = o; i < CTRL * NBN; i += 256) {
        int f = i >> 3, bn = i & 7;
        wT[f][bn] = out_w[(bn * N_RES + r) * CTRL + f];
    }
    __syncthreads();
    const float4* Gr = G4 + (size_t)r * N_SAMPLES;
    run_duo(2 * dp + 1,   o, r, Gr, wT, dfr, xout);
    run_duo(127 - 2 * dp, o, r, Gr, wT, dfr, xout);
}

// ---------------------------------------------------------------- K6: tanh(gain*x) summed over r
__global__ __launch_bounds__(256) void k6_out(const __hip_bfloat16* __restrict__ xin,
                                              const float* __restrict__ gains,
                                              float* __restrict__ out) {
    __shared__ float gabs[N_RES];
    int bid = blockIdx.x;
    int sc = bid & 127, bn = bid >> 7;
    int o = threadIdx.x;
    if (o < N_RES) gabs[o] = fabsf(gains[o]);
    __syncthreads();
    int s = sc * STEP + o;
    float acc = 0.f;
    #pragma unroll 4
    for (int rr = 0; rr < N_RES; ++rr) {
        float xf = __bfloat162float(xin[(size_t)(bn * N_RES + rr) * N_SAMPLES + s]);
        acc += tanhf(xf * gabs[rr]);
    }
    out[bn * N_SAMPLES + s] = acc;
}

// ---------------------------------------------------------------- launch
extern "C" void kernel_launch(void* const* d_in, const int* in_sizes, int n_in,
                              void* d_out, int out_size, void* d_ws, size_t ws_size,
                              hipStream_t stream) {
    const float* control = (const float*)d_in[0];
    const float* defo    = (const float*)d_in[1];
    const float* router  = (const float*)d_in[2];
    const float* gains   = (const float*)d_in[3];
    const float* amp     = (const float*)d_in[4];
    const float* phase   = (const float*)d_in[5];
    const float* decay   = (const float*)d_in[6];
    const float* noise   = (const float*)d_in[7];

    float* out_summed = (float*)d_out;
    float* out_w      = (float*)d_out + NBN * N_SAMPLES;

    // ws layout:
    //  slot0 [0, 18.87MB): Bbf (bf16, 9437184) ; G4 aliases (16.78MB, written in k3 after B dead)
    //  slot1 [18.87, 35.65MB): res_raw f32 (16.78MB); Pa/Za/L2a alias (dead before k1m);
    //                          xout bf16 aliases (written in k5 after res dead)
    //  tail: Afrag bf16 294912B, normp 4KB, inv_norm 512B, dfr 16KB
    char* ws = (char*)d_ws;
    const size_t BSZ = (size_t)128 * NKS * 128 * 32 * 2;       // 18,874,368
    const size_t RSZ = (size_t)N_RES * EXPR * N_SAMPLES * 4;   // 16,777,216
    __hip_bfloat16* Bbf = (__hip_bfloat16*)ws;
    float4* G4 = (float4*)ws;
    char* slot1 = ws + BSZ;
    float* res_raw = (float*)slot1;
    float* Pa  = (float*)slot1;
    float* Za  = Pa + 128 * KT;
    float* L2a = Za + 128 * KT;
    __hip_bfloat16* xout = (__hip_bfloat16*)slot1;
    char* tail = slot1 + RSZ;
    __hip_bfloat16* Afrag = (__hip_bfloat16*)tail;             // 147456 elts
    float* normp = (float*)(tail + 294912);                    // 1024 floats
    float* inv_norm = normp + 1024;                            // 128 floats
    float* dfr = inv_norm + 128;                               // 4096 floats

    k0_params<<<288, 256, 0, stream>>>(amp, phase, decay, Pa, Za, L2a);
    k0a_afrag<<<576, 256, 0, stream>>>(Afrag);
    k0b_bgen<<<36864, 256, 0, stream>>>(Pa, Za, L2a, Bbf);
    k4a_route<<<(NBN * N_RES * CTRL) / 256, 256, 0, stream>>>(control, router, out_w);
    k4b_dfr<<<(NBN * CTRL + 255) / 256, 256, 0, stream>>>(defo, dfr);
    k1m<<<1024, 256, 0, stream>>>((const short*)Afrag, (const short*)Bbf, res_raw, normp);
    k2_fin<<<1, 128, 0, stream>>>(normp, inv_norm);
    k3_impconv<<<N_RES * N_FRAMES, 256, 0, stream>>>(res_raw, inv_norm, noise, G4);
    k5_conv<<<1024, 256, 0, stream>>>(G4, out_w, dfr, xout);
    k6_out<<<NBN * N_FRAMES, 256, 0, stream>>>(xout, gains, out_summed);
}

// Round 5
// 156.289 us; speedup vs baseline: 3.2368x; 1.0680x over previous
//
#include <hip/hip_runtime.h>
#include <hip/hip_bf16.h>
#include <math.h>

#define N_SAMPLES 32768
#define STEP 256
#define N_FRAMES 128
#define N_COEFFS 257
#define KT 576            // stacked K: 288 (cos/Cre) + 288 (sin/-Cim)
#define NKS 18            // K-steps of 32
#define CPD 16
#define N_RES 32
#define EXPR 4
#define CTRL 128
#define NBN 8
#define PI_F 3.14159265358979323846f

typedef __attribute__((ext_vector_type(8))) short bf16x8;
typedef __attribute__((ext_vector_type(4))) float f32x4;

__device__ __forceinline__ unsigned short f2bf(float x) {
    __hip_bfloat16 h = __float2bfloat16(x);
    return *(unsigned short*)&h;
}

// ---------------------------------------------------------------- K0: per-(re,k) scalar params (P, Z, L2)
__global__ __launch_bounds__(256) void k0_params(const float* __restrict__ amp,
                                                 const float* __restrict__ phase,
                                                 const float* __restrict__ decay,
                                                 float* __restrict__ Pa, float* __restrict__ Za,
                                                 float* __restrict__ L2a) {
    int idx = blockIdx.x * 256 + threadIdx.x;     // 128*576 = 73728
    if (idx >= 128 * KT) return;
    int k  = idx % KT;
    int re = idx / KT;
    int r = re >> 2, e = re & 3;
    int kk = (k < 288) ? k : k - 288;
    float P = 0.f, Z = 0.f, L2v = 0.f;
    if (kk < N_COEFFS) {
        int src = (r * N_COEFFS + kk) * EXPR + e;
        float m  = fabsf(amp[src]) + 1e-12f;
        float ph = tanhf(phase[src]) * PI_F;
        float sg = 1.0f / (1.0f + expf(-decay[src]));
        float d  = 0.5f + 0.45f * sg;
        float wk = (kk == 0 || kk == 256) ? (1.0f / 512.0f) : (2.0f / 512.0f);
        float c  = (k < 288) ? (wk * m * cosf(ph)) : (-wk * m * sinf(ph));
        float sgn = (kk & 1) ? -1.f : 1.f;
        P = c * (d + sgn);
        Z = c * d;
        L2v = log2f(d);
    }
    Pa[idx] = P; Za[idx] = Z; L2a[idx] = L2v;
}

// ---------------------------------------------------------------- K0a: A (twiddles) in MFMA frag order, bf16
__global__ __launch_bounds__(256) void k0a_afrag(__hip_bfloat16* __restrict__ Afrag) {
    int f = blockIdx.x * 256 + threadIdx.x;       // 16*18*64*8 = 147456
    int e = f & 7;
    int l = (f >> 3) & 63;
    int s = (f >> 9) % NKS;
    int ot = f / (NKS * 512);
    int o = ot * 16 + (l & 15);
    int k = s * 32 + ((e >> 2) << 4) + (((l >> 4) & 3) << 2) + (e & 3);
    float v;
    if (k < 288) v = cosf((float)((k * o) & 511) * (2.0f * PI_F / 512.0f));
    else { int kk = k - 288; v = sinf((float)((kk * o) & 511) * (2.0f * PI_F / 512.0f)); }
    Afrag[f] = __float2bfloat16(v);
}

// ---------------------------------------------------------------- K0b: B matrix bf16, frag-order rows
__global__ __launch_bounds__(256) void k0b_bgen(const float* __restrict__ Pa, const float* __restrict__ Za,
                                                const float* __restrict__ L2a,
                                                __hip_bfloat16* __restrict__ Bbf) {
    int f = blockIdx.x * 256 + threadIdx.x;       // 128*18*128*32 = 9437184
    int p = f & 31;
    int j = (f >> 5) & 127;
    int rs = f >> 12;
    int s = rs % NKS;
    int re = rs / NKS;
    int g = p >> 3, e = p & 7;
    int k = s * 32 + ((e >> 2) << 4) + (g << 2) + (e & 3);
    int ix = re * KT + k;
    float val = (j == 0) ? Za[ix] : Pa[ix] * exp2f((float)j * L2a[ix]);
    Bbf[f] = __float2bfloat16(val);
}

// ---------------------------------------------------------------- K1m: MFMA resonance GEMM (256o x 16384n, K=576)
__global__ __launch_bounds__(256) void k1m(const short* __restrict__ Afrag,
                                           const short* __restrict__ Bbf,
                                           float* __restrict__ res_raw,
                                           float* __restrict__ normp) {
    __shared__ short Bs[2][2048];
    __shared__ float red[256];
    int tid = threadIdx.x;
    int l = tid & 63, w = tid >> 6;
    int bid = blockIdx.x;             // 1024
    int x = bid & 7, m = bid >> 3;
    int re = x * 16 + (m >> 3);
    int sub = m & 7;
    int bx = sub >> 1, jb = sub & 1;

    int otile = bx * 4 + w;
    bf16x8 af[NKS];
    #pragma unroll
    for (int s = 0; s < NKS; ++s)
        af[s] = *(const bf16x8*)(Afrag + ((size_t)(otile * NKS + s) * 64 + l) * 8);

    f32x4 acc[4] = {{0.f,0.f,0.f,0.f},{0.f,0.f,0.f,0.f},{0.f,0.f,0.f,0.f},{0.f,0.f,0.f,0.f}};
    const short* Bsrc = Bbf + (size_t)re * (NKS * 4096) + jb * 2048;

    __builtin_amdgcn_global_load_lds(
        (__attribute__((address_space(1))) const void*)(Bsrc + tid * 8),
        (__attribute__((address_space(3))) void*)(&Bs[0][tid * 8]), 16, 0, 0);

    int boff = (l & 15) * 32 + (l >> 4) * 8;
    int cur = 0;
    #pragma unroll
    for (int s = 0; s < NKS; ++s) {
        __syncthreads();
        if (s < NKS - 1)
            __builtin_amdgcn_global_load_lds(
                (__attribute__((address_space(1))) const void*)(Bsrc + (s + 1) * 4096 + tid * 8),
                (__attribute__((address_space(3))) void*)(&Bs[cur ^ 1][tid * 8]), 16, 0, 0);
        const short* bp = &Bs[cur][0];
        #pragma unroll
        for (int jt = 0; jt < 4; ++jt) {
            bf16x8 bf = *(const bf16x8*)(bp + jt * 512 + boff);
            acc[jt] = __builtin_amdgcn_mfma_f32_16x16x32_bf16(af[s], bf, acc[jt], 0, 0, 0);
        }
        cur ^= 1;
    }

    int o0 = otile * 16 + ((l >> 4) & 3) * 4;
    int jbase = jb * 64 + (l & 15);
    float s2 = 0.f;
    #pragma unroll
    for (int jt = 0; jt < 4; ++jt) {
        int j = jbase + jt * 16;
        float4 v = make_float4(acc[jt][0], acc[jt][1], acc[jt][2], acc[jt][3]);
        s2 += v.x * v.x + v.y * v.y + v.z * v.z + v.w * v.w;
        *(float4*)&res_raw[(size_t)re * N_SAMPLES + j * STEP + o0] = v;
    }
    red[tid] = s2;
    __syncthreads();
    for (int st = 128; st > 0; st >>= 1) {
        if (tid < st) red[tid] += red[tid + st];
        __syncthreads();
    }
    if (tid == 0) normp[re * 8 + bx * 2 + jb] = red[0];
}

// ---------------------------------------------------------------- K2: finalize inverse norms
__global__ void k2_fin(const float* __restrict__ normp, float* __restrict__ inv_norm) {
    int t = threadIdx.x;
    if (t >= 128) return;
    float s = 0.f;
    #pragma unroll
    for (int i = 0; i < 8; ++i) s += normp[t * 8 + i];
    inv_norm[t] = 1.0f / (sqrtf(s) + 1e-8f);
}

// ---------------------------------------------------------------- K3: impulse FIR -> Gbf (bf16x4 over e)
__global__ __launch_bounds__(256) void k3_impconv(const float* __restrict__ res_raw,
                                                  const float* __restrict__ inv_norm,
                                                  const float* __restrict__ noise,
                                                  unsigned int* __restrict__ Gbf_u) {
    __shared__ float st[EXPR][384];
    __shared__ float imp[128];
    int blk = blockIdx.x;
    int j = blk % N_FRAMES;
    int r = blk / N_FRAMES;
    int tid = threadIdx.x;
    for (int i = tid; i < EXPR * 384; i += 256) {
        int e = i / 384, ii = i % 384;
        int g = j * STEP - 127 + ii;
        float v = 0.f;
        if (g >= 0 && g < N_SAMPLES) v = res_raw[(size_t)(r * EXPR + e) * N_SAMPLES + g] * inv_norm[r * EXPR + e];
        st[e][ii] = v;
    }
    if (tid < 128)
        imp[tid] = (0.54f - 0.46f * cosf((2.0f * PI_F / 128.0f) * (float)tid)) * noise[tid];
    __syncthreads();
    float a0 = 0.f, a1 = 0.f, a2 = 0.f, a3 = 0.f;
    #pragma unroll 4
    for (int u = 0; u < 128; ++u) {
        float w = imp[u];
        int idx = tid + 127 - u;
        a0 = fmaf(w, st[0][idx], a0);
        a1 = fmaf(w, st[1][idx], a1);
        a2 = fmaf(w, st[2][idx], a2);
        a3 = fmaf(w, st[3][idx], a3);
    }
    // pack 4 bf16 (e fastest) -> 8B store at [r][s][e]
    unsigned int lo = (unsigned int)f2bf(a0) | ((unsigned int)f2bf(a1) << 16);
    unsigned int hi = (unsigned int)f2bf(a2) | ((unsigned int)f2bf(a3) << 16);
    size_t base = ((size_t)r * N_SAMPLES + j * STEP + tid) * 2;   // in uint units
    Gbf_u[base] = lo;
    Gbf_u[base + 1] = hi;
}

// ---------------------------------------------------------------- K4a: routed weights (= before_upsample output)
__global__ __launch_bounds__(256) void k4a_route(const float* __restrict__ control,
                                                 const float* __restrict__ router,
                                                 float* __restrict__ out_w) {
    int idx = blockIdx.x * 256 + threadIdx.x;
    int f  = idx % CTRL;
    int r  = (idx / CTRL) % N_RES;
    int bn = idx / (CTRL * N_RES);
    float s = 0.f;
    #pragma unroll
    for (int c = 0; c < CPD; ++c)
        s += control[(bn * CPD + c) * CTRL + f] * router[c * N_RES + r];
    out_w[idx] = s;
}

// ---------------------------------------------------------------- K4b: softmax over expressions per ctrl frame
__global__ __launch_bounds__(256) void k4b_dfr(const float* __restrict__ defo, float* __restrict__ d_frames) {
    int idx = blockIdx.x * 256 + threadIdx.x;
    if (idx >= NBN * CTRL) return;
    int f = idx % CTRL, bn = idx / CTRL;
    float v[EXPR]; float mx = -1e30f;
    #pragma unroll
    for (int e = 0; e < EXPR; ++e) {
        float xv = defo[(bn * EXPR + e) * CTRL + f] + (e == 0 ? 1.0f : 0.0f);
        v[e] = xv; mx = fmaxf(mx, xv);
    }
    float sum = 0.f;
    #pragma unroll
    for (int e = 0; e < EXPR; ++e) { v[e] = expf(v[e] - mx); sum += v[e]; }
    float inv = 1.0f / sum;
    #pragma unroll
    for (int e = 0; e < EXPR; ++e) d_frames[(bn * EXPR + e) * CTRL + f] = v[e] * inv;
}

// ---------------------------------------------------------------- K4w: Toeplitz W fragments, bf16 frag order
__global__ __launch_bounds__(256) void k4w(const float* __restrict__ out_w,
                                           short* __restrict__ Wf) {
    const int mt_of[20] = {0,1,2,2,3,3,4,4,4,5,5,5,6,6,6,6,7,7,7,7};
    const int kt_of[20] = {0,0,0,1,0,1,0,1,2,0,1,2,0,1,2,3,0,1,2,3};
    int id = blockIdx.x * 256 + threadIdx.x;   // ((r*8+bn)*20+pr)*64 + l ; total 327680
    if (id >= 32 * 8 * 20 * 64) return;
    int l = id & 63;
    int pr = (id >> 6) % 20;
    int rb = id / (64 * 20);
    int bn = rb & 7, r = rb >> 3;
    int mt = mt_of[pr], kt = kt_of[pr];
    int j = mt * 16 + (l & 15);
    int g4 = (l >> 4) & 3;
    const float* wp = out_w + (bn * N_RES + r) * CTRL;
    bf16x8 v;
    #pragma unroll
    for (int ee = 0; ee < 8; ++ee) {
        int f = kt * 32 + ((ee >> 2) << 4) + (g4 << 2) + (ee & 3);
        float val = (j >= f) ? wp[j - f] : 0.f;
        v[ee] = (short)f2bf(val);
    }
    *(bf16x8*)(Wf + (size_t)id * 8) = v;
}

// ---------------------------------------------------------------- K5m: MFMA Toeplitz conv + fused de/e-sum epilogue
__global__ __launch_bounds__(256) void k5m(const short* __restrict__ Gbf,
                                           const short* __restrict__ Wf,
                                           const float* __restrict__ dfr,
                                           __hip_bfloat16* __restrict__ xout) {
    const int mt_of[20] = {0,1,2,2,3,3,4,4,4,5,5,5,6,6,6,6,7,7,7,7};
    const int kt_of[20] = {0,0,0,1,0,1,0,1,2,0,1,2,0,1,2,3,0,1,2,3};
    __shared__ float dsm[NBN * EXPR * CTRL];   // 16KB
    int tid = threadIdx.x;
    int bid = blockIdx.x;                       // 256: same-r blocks share an XCD
    int r  = (bid & 7) * 4 + ((bid >> 3) & 3);
    int ob = bid >> 5;
    for (int i = tid; i < NBN * EXPR * CTRL / 4; i += 256)
        ((float4*)dsm)[i] = ((const float4*)dfr)[i];
    __syncthreads();
    int l = tid & 63, w = tid >> 6;
    int ot = w & 1, bnh = w >> 1;
    int ocol = ob * 32 + ot * 16 + (l & 15);
    int g4 = (l >> 4) & 3;
    float co = ((float)ocol + 0.5f) * (1.0f / 256.0f) - 0.5f;

    // ---- gather 16 B-frags (G) into regs, reused across all bn
    bf16x8 bfr[4][4];  // [e][kt]
    const short* gb = Gbf + (size_t)r * (N_SAMPLES * 4);
    #pragma unroll
    for (int e = 0; e < 4; ++e)
        #pragma unroll
        for (int kt = 0; kt < 4; ++kt) {
            bf16x8 v;
            #pragma unroll
            for (int ee = 0; ee < 8; ++ee) {
                int f = kt * 32 + ((ee >> 2) << 4) + (g4 << 2) + (ee & 3);
                v[ee] = gb[((size_t)(f * 256 + ocol)) * 4 + e];
            }
            bfr[e][kt] = v;
        }

    for (int bi = 0; bi < 4; ++bi) {
        int bn = bnh * 4 + bi;
        const short* wfb = Wf + ((size_t)((r * 8 + bn) * 20)) * 512 + l * 8;
        float xsum[8][4];
        #pragma unroll
        for (int mt = 0; mt < 8; ++mt)
            #pragma unroll
            for (int q = 0; q < 4; ++q) xsum[mt][q] = 0.f;

        #pragma unroll
        for (int eh = 0; eh < 2; ++eh) {
            f32x4 acc[2][8] = {};
            #pragma unroll
            for (int pr = 0; pr < 20; ++pr) {
                bf16x8 wv = *(const bf16x8*)(wfb + pr * 512);
                int mt = mt_of[pr], kt = kt_of[pr];
                acc[0][mt] = __builtin_amdgcn_mfma_f32_16x16x32_bf16(wv, bfr[eh * 2][kt],     acc[0][mt], 0, 0, 0);
                acc[1][mt] = __builtin_amdgcn_mfma_f32_16x16x32_bf16(wv, bfr[eh * 2 + 1][kt], acc[1][mt], 0, 0, 0);
            }
            // fuse de weights for the two e's of this half
            #pragma unroll
            for (int mt = 0; mt < 8; ++mt) {
                #pragma unroll
                for (int q = 0; q < 4; ++q) {
                    int j = mt * 16 + g4 * 4 + q;
                    float pos = fminf(fmaxf((float)j + co, 0.0f), 127.0f);
                    int lo = (int)floorf(pos);
                    int hi = min(lo + 1, 127);
                    float wg = pos - (float)lo;
                    #pragma unroll
                    for (int ei = 0; ei < 2; ++ei) {
                        int e = eh * 2 + ei;
                        const float* dp = dsm + (bn * EXPR + e) * CTRL;
                        float de = dp[lo] * (1.0f - wg) + dp[hi] * wg;
                        xsum[mt][q] = fmaf(de, acc[ei][mt][q], xsum[mt][q]);
                    }
                }
            }
        }
        // write bf16
        __hip_bfloat16* xo = xout + (size_t)(bn * N_RES + r) * N_SAMPLES;
        #pragma unroll
        for (int mt = 0; mt < 8; ++mt)
            #pragma unroll
            for (int q = 0; q < 4; ++q) {
                int j = mt * 16 + g4 * 4 + q;
                xo[j * STEP + ocol] = __float2bfloat16(xsum[mt][q]);
            }
    }
}

// ---------------------------------------------------------------- K6: tanh(gain*x) summed over r
__global__ __launch_bounds__(256) void k6_out(const __hip_bfloat16* __restrict__ xin,
                                              const float* __restrict__ gains,
                                              float* __restrict__ out) {
    __shared__ float gabs[N_RES];
    int bid = blockIdx.x;
    int sc = bid & 127, bn = bid >> 7;
    int o = threadIdx.x;
    if (o < N_RES) gabs[o] = fabsf(gains[o]);
    __syncthreads();
    int s = sc * STEP + o;
    float acc = 0.f;
    #pragma unroll 4
    for (int rr = 0; rr < N_RES; ++rr) {
        float xf = __bfloat162float(xin[(size_t)(bn * N_RES + rr) * N_SAMPLES + s]);
        acc += tanhf(xf * gabs[rr]);
    }
    out[bn * N_SAMPLES + s] = acc;
}

// ---------------------------------------------------------------- launch
extern "C" void kernel_launch(void* const* d_in, const int* in_sizes, int n_in,
                              void* d_out, int out_size, void* d_ws, size_t ws_size,
                              hipStream_t stream) {
    const float* control = (const float*)d_in[0];
    const float* defo    = (const float*)d_in[1];
    const float* router  = (const float*)d_in[2];
    const float* gains   = (const float*)d_in[3];
    const float* amp     = (const float*)d_in[4];
    const float* phase   = (const float*)d_in[5];
    const float* decay   = (const float*)d_in[6];
    const float* noise   = (const float*)d_in[7];

    float* out_summed = (float*)d_out;
    float* out_w      = (float*)d_out + NBN * N_SAMPLES;

    // ws layout:
    //  slot0 [0, 18.87MB): Bbf (k0b->k1m). After k1m dead: Gbf bf16 (8MB, k3->k5m)
    //                      + Wf bf16 (5.25MB at +8MB, k4w->k5m)
    //  slot1 [18.87, 35.65MB): res_raw f32 (k1m->k3); Pa/Za/L2a alias (dead before k1m);
    //                          xout bf16 alias (k5m->k6)
    //  tail: Afrag 294912B, normp 4KB, inv_norm 512B, dfr 16KB
    char* ws = (char*)d_ws;
    const size_t BSZ = (size_t)128 * NKS * 128 * 32 * 2;       // 18,874,368
    const size_t RSZ = (size_t)N_RES * EXPR * N_SAMPLES * 4;   // 16,777,216
    __hip_bfloat16* Bbf = (__hip_bfloat16*)ws;
    short* Gbf = (short*)ws;                                   // 8,388,608 B
    short* Wf  = (short*)(ws + 8388608);                       // 5,242,880 B
    char* slot1 = ws + BSZ;
    float* res_raw = (float*)slot1;
    float* Pa  = (float*)slot1;
    float* Za  = Pa + 128 * KT;
    float* L2a = Za + 128 * KT;
    __hip_bfloat16* xout = (__hip_bfloat16*)slot1;
    char* tail = slot1 + RSZ;
    __hip_bfloat16* Afrag = (__hip_bfloat16*)tail;             // 147456 elts
    float* normp = (float*)(tail + 294912);                    // 1024 floats
    float* inv_norm = normp + 1024;                            // 128 floats
    float* dfr = inv_norm + 128;                               // 4096 floats

    k0_params<<<288, 256, 0, stream>>>(amp, phase, decay, Pa, Za, L2a);
    k0a_afrag<<<576, 256, 0, stream>>>(Afrag);
    k0b_bgen<<<36864, 256, 0, stream>>>(Pa, Za, L2a, Bbf);
    k4a_route<<<(NBN * N_RES * CTRL) / 256, 256, 0, stream>>>(control, router, out_w);
    k4b_dfr<<<(NBN * CTRL + 255) / 256, 256, 0, stream>>>(defo, dfr);
    k1m<<<1024, 256, 0, stream>>>((const short*)Afrag, (const short*)Bbf, res_raw, normp);
    k2_fin<<<1, 128, 0, stream>>>(normp, inv_norm);
    k4w<<<1280, 256, 0, stream>>>(out_w, Wf);
    k3_impconv<<<N_RES * N_FRAMES, 256, 0, stream>>>(res_raw, inv_norm, noise, (unsigned int*)Gbf);
    k5m<<<256, 256, 0, stream>>>(Gbf, Wf, dfr, xout);
    k6_out<<<NBN * N_FRAMES, 256, 0, stream>>>(xout, gains, out_summed);
}

// Round 6
// 152.919 us; speedup vs baseline: 3.3082x; 1.0220x over previous
//
#include <hip/hip_runtime.h>
#include <hip/hip_bf16.h>
#include <math.h>

#define N_SAMPLES 32768
#define STEP 256
#define N_FRAMES 128
#define N_COEFFS 257
#define KT 576            // stacked K: 288 (cos/Cre) + 288 (sin/-Cim)
#define NKS 18            // K-steps of 32
#define CPD 16
#define N_RES 32
#define EXPR 4
#define CTRL 128
#define NBN 8
#define PI_F 3.14159265358979323846f

typedef __attribute__((ext_vector_type(8))) short bf16x8;
typedef __attribute__((ext_vector_type(4))) float f32x4;

__device__ __forceinline__ unsigned short f2bf(float x) {
    __hip_bfloat16 h = __float2bfloat16(x);
    return *(unsigned short*)&h;
}

// ---------------------------------------------------------------- K0: per-(re,k) scalar params (P, Z, L2)
__global__ __launch_bounds__(256) void k0_params(const float* __restrict__ amp,
                                                 const float* __restrict__ phase,
                                                 const float* __restrict__ decay,
                                                 float* __restrict__ Pa, float* __restrict__ Za,
                                                 float* __restrict__ L2a) {
    int idx = blockIdx.x * 256 + threadIdx.x;     // 128*576 = 73728
    if (idx >= 128 * KT) return;
    int k  = idx % KT;
    int re = idx / KT;
    int r = re >> 2, e = re & 3;
    int kk = (k < 288) ? k : k - 288;
    float P = 0.f, Z = 0.f, L2v = 0.f;
    if (kk < N_COEFFS) {
        int src = (r * N_COEFFS + kk) * EXPR + e;
        float m  = fabsf(amp[src]) + 1e-12f;
        float ph = tanhf(phase[src]) * PI_F;
        float sg = 1.0f / (1.0f + expf(-decay[src]));
        float d  = 0.5f + 0.45f * sg;
        float wk = (kk == 0 || kk == 256) ? (1.0f / 512.0f) : (2.0f / 512.0f);
        float c  = (k < 288) ? (wk * m * cosf(ph)) : (-wk * m * sinf(ph));
        float sgn = (kk & 1) ? -1.f : 1.f;
        P = c * (d + sgn);
        Z = c * d;
        L2v = log2f(d);
    }
    Pa[idx] = P; Za[idx] = Z; L2a[idx] = L2v;
}

// ---------------------------------------------------------------- K0a: A (twiddles) in MFMA frag order, bf16
__global__ __launch_bounds__(256) void k0a_afrag(__hip_bfloat16* __restrict__ Afrag) {
    int f = blockIdx.x * 256 + threadIdx.x;       // 16*18*64*8 = 147456
    int e = f & 7;
    int l = (f >> 3) & 63;
    int s = (f >> 9) % NKS;
    int ot = f / (NKS * 512);
    int o = ot * 16 + (l & 15);
    int k = s * 32 + ((e >> 2) << 4) + (((l >> 4) & 3) << 2) + (e & 3);
    float v;
    if (k < 288) v = cosf((float)((k * o) & 511) * (2.0f * PI_F / 512.0f));
    else { int kk = k - 288; v = sinf((float)((kk * o) & 511) * (2.0f * PI_F / 512.0f)); }
    Afrag[f] = __float2bfloat16(v);
}

// ---------------------------------------------------------------- K0b: B matrix bf16, frag-order rows
__global__ __launch_bounds__(256) void k0b_bgen(const float* __restrict__ Pa, const float* __restrict__ Za,
                                                const float* __restrict__ L2a,
                                                __hip_bfloat16* __restrict__ Bbf) {
    int f = blockIdx.x * 256 + threadIdx.x;       // 128*18*128*32 = 9437184
    int p = f & 31;
    int j = (f >> 5) & 127;
    int rs = f >> 12;
    int s = rs % NKS;
    int re = rs / NKS;
    int g = p >> 3, e = p & 7;
    int k = s * 32 + ((e >> 2) << 4) + (g << 2) + (e & 3);
    int ix = re * KT + k;
    float val = (j == 0) ? Za[ix] : Pa[ix] * exp2f((float)j * L2a[ix]);
    Bbf[f] = __float2bfloat16(val);
}

// ---------------------------------------------------------------- K1m: MFMA resonance GEMM (256o x 16384n, K=576)
__global__ __launch_bounds__(256) void k1m(const short* __restrict__ Afrag,
                                           const short* __restrict__ Bbf,
                                           float* __restrict__ res_raw,
                                           float* __restrict__ normp) {
    __shared__ short Bs[2][2048];
    __shared__ float red[256];
    int tid = threadIdx.x;
    int l = tid & 63, w = tid >> 6;
    int bid = blockIdx.x;             // 1024
    int x = bid & 7, m = bid >> 3;
    int re = x * 16 + (m >> 3);
    int sub = m & 7;
    int bx = sub >> 1, jb = sub & 1;

    int otile = bx * 4 + w;
    bf16x8 af[NKS];
    #pragma unroll
    for (int s = 0; s < NKS; ++s)
        af[s] = *(const bf16x8*)(Afrag + ((size_t)(otile * NKS + s) * 64 + l) * 8);

    f32x4 acc[4] = {{0.f,0.f,0.f,0.f},{0.f,0.f,0.f,0.f},{0.f,0.f,0.f,0.f},{0.f,0.f,0.f,0.f}};
    const short* Bsrc = Bbf + (size_t)re * (NKS * 4096) + jb * 2048;

    __builtin_amdgcn_global_load_lds(
        (__attribute__((address_space(1))) const void*)(Bsrc + tid * 8),
        (__attribute__((address_space(3))) void*)(&Bs[0][tid * 8]), 16, 0, 0);

    int boff = (l & 15) * 32 + (l >> 4) * 8;
    int cur = 0;
    #pragma unroll
    for (int s = 0; s < NKS; ++s) {
        __syncthreads();
        if (s < NKS - 1)
            __builtin_amdgcn_global_load_lds(
                (__attribute__((address_space(1))) const void*)(Bsrc + (s + 1) * 4096 + tid * 8),
                (__attribute__((address_space(3))) void*)(&Bs[cur ^ 1][tid * 8]), 16, 0, 0);
        const short* bp = &Bs[cur][0];
        #pragma unroll
        for (int jt = 0; jt < 4; ++jt) {
            bf16x8 bf = *(const bf16x8*)(bp + jt * 512 + boff);
            acc[jt] = __builtin_amdgcn_mfma_f32_16x16x32_bf16(af[s], bf, acc[jt], 0, 0, 0);
        }
        cur ^= 1;
    }

    int o0 = otile * 16 + ((l >> 4) & 3) * 4;
    int jbase = jb * 64 + (l & 15);
    float s2 = 0.f;
    #pragma unroll
    for (int jt = 0; jt < 4; ++jt) {
        int j = jbase + jt * 16;
        float4 v = make_float4(acc[jt][0], acc[jt][1], acc[jt][2], acc[jt][3]);
        s2 += v.x * v.x + v.y * v.y + v.z * v.z + v.w * v.w;
        *(float4*)&res_raw[(size_t)re * N_SAMPLES + j * STEP + o0] = v;
    }
    red[tid] = s2;
    __syncthreads();
    for (int st = 128; st > 0; st >>= 1) {
        if (tid < st) red[tid] += red[tid + st];
        __syncthreads();
    }
    if (tid == 0) normp[re * 8 + bx * 2 + jb] = red[0];
}

// ---------------------------------------------------------------- K2: finalize inverse norms
__global__ void k2_fin(const float* __restrict__ normp, float* __restrict__ inv_norm) {
    int t = threadIdx.x;
    if (t >= 128) return;
    float s = 0.f;
    #pragma unroll
    for (int i = 0; i < 8; ++i) s += normp[t * 8 + i];
    inv_norm[t] = 1.0f / (sqrtf(s) + 1e-8f);
}

// ---------------------------------------------------------------- K3: impulse FIR -> Gbf in MFMA frag order
// Gbf layout: [r][e][kt][o 256][p 32], p = lane-order position of kappa = f & 31
__global__ __launch_bounds__(256) void k3_impconv(const float* __restrict__ res_raw,
                                                  const float* __restrict__ inv_norm,
                                                  const float* __restrict__ noise,
                                                  short* __restrict__ Gbf) {
    __shared__ float st[EXPR][384];
    __shared__ float imp[128];
    int blk = blockIdx.x;
    int j = blk % N_FRAMES;          // frame index f
    int r = blk / N_FRAMES;
    int tid = threadIdx.x;           // o
    for (int i = tid; i < EXPR * 384; i += 256) {
        int e = i / 384, ii = i % 384;
        int g = j * STEP - 127 + ii;
        float v = 0.f;
        if (g >= 0 && g < N_SAMPLES) v = res_raw[(size_t)(r * EXPR + e) * N_SAMPLES + g] * inv_norm[r * EXPR + e];
        st[e][ii] = v;
    }
    if (tid < 128)
        imp[tid] = (0.54f - 0.46f * cosf((2.0f * PI_F / 128.0f) * (float)tid)) * noise[tid];
    __syncthreads();
    float a[4] = {0.f, 0.f, 0.f, 0.f};
    #pragma unroll 4
    for (int u = 0; u < 128; ++u) {
        float w = imp[u];
        int idx = tid + 127 - u;
        a[0] = fmaf(w, st[0][idx], a[0]);
        a[1] = fmaf(w, st[1][idx], a[1]);
        a[2] = fmaf(w, st[2][idx], a[2]);
        a[3] = fmaf(w, st[3][idx], a[3]);
    }
    int kt = j >> 5;
    int ka = j & 31;
    int p = ((ka >> 2) & 3) * 8 + ((ka >> 4) << 2) + (ka & 3);
    #pragma unroll
    for (int e = 0; e < 4; ++e)
        Gbf[(((size_t)(r * 4 + e) * 4 + kt) * 256 + tid) * 32 + p] = (short)f2bf(a[e]);
}

// ---------------------------------------------------------------- K4a: routed weights (= before_upsample output)
__global__ __launch_bounds__(256) void k4a_route(const float* __restrict__ control,
                                                 const float* __restrict__ router,
                                                 float* __restrict__ out_w) {
    int idx = blockIdx.x * 256 + threadIdx.x;
    int f  = idx % CTRL;
    int r  = (idx / CTRL) % N_RES;
    int bn = idx / (CTRL * N_RES);
    float s = 0.f;
    #pragma unroll
    for (int c = 0; c < CPD; ++c)
        s += control[(bn * CPD + c) * CTRL + f] * router[c * N_RES + r];
    out_w[idx] = s;
}

// ---------------------------------------------------------------- K4b: softmax over expressions per ctrl frame
__global__ __launch_bounds__(256) void k4b_dfr(const float* __restrict__ defo, float* __restrict__ d_frames) {
    int idx = blockIdx.x * 256 + threadIdx.x;
    if (idx >= NBN * CTRL) return;
    int f = idx % CTRL, bn = idx / CTRL;
    float v[EXPR]; float mx = -1e30f;
    #pragma unroll
    for (int e = 0; e < EXPR; ++e) {
        float xv = defo[(bn * EXPR + e) * CTRL + f] + (e == 0 ? 1.0f : 0.0f);
        v[e] = xv; mx = fmaxf(mx, xv);
    }
    float sum = 0.f;
    #pragma unroll
    for (int e = 0; e < EXPR; ++e) { v[e] = expf(v[e] - mx); sum += v[e]; }
    float inv = 1.0f / sum;
    #pragma unroll
    for (int e = 0; e < EXPR; ++e) d_frames[(bn * EXPR + e) * CTRL + f] = v[e] * inv;
}

// ---------------------------------------------------------------- K4w: Toeplitz W fragments, bf16 frag order
__global__ __launch_bounds__(256) void k4w(const float* __restrict__ out_w,
                                           short* __restrict__ Wf) {
    const int mt_of[20] = {0,1,2,2,3,3,4,4,4,5,5,5,6,6,6,6,7,7,7,7};
    const int kt_of[20] = {0,0,0,1,0,1,0,1,2,0,1,2,0,1,2,3,0,1,2,3};
    int id = blockIdx.x * 256 + threadIdx.x;   // ((r*8+bn)*20+pr)*64 + l ; total 327680
    if (id >= 32 * 8 * 20 * 64) return;
    int l = id & 63;
    int pr = (id >> 6) % 20;
    int rb = id / (64 * 20);
    int bn = rb & 7, r = rb >> 3;
    int mt = mt_of[pr], kt = kt_of[pr];
    int j = mt * 16 + (l & 15);
    int g4 = (l >> 4) & 3;
    const float* wp = out_w + (bn * N_RES + r) * CTRL;
    bf16x8 v;
    #pragma unroll
    for (int ee = 0; ee < 8; ++ee) {
        int f = kt * 32 + ((ee >> 2) << 4) + (g4 << 2) + (ee & 3);
        float val = (j >= f) ? wp[j - f] : 0.f;
        v[ee] = (short)f2bf(val);
    }
    *(bf16x8*)(Wf + (size_t)id * 8) = v;
}

// ---------------------------------------------------------------- K5m v2: MFMA Toeplitz conv, LDS-staged B, fused epilogue
__global__ __launch_bounds__(256, 2) void k5m(const short* __restrict__ Gbf,
                                              const short* __restrict__ Wf,
                                              const float* __restrict__ dfr,
                                              __hip_bfloat16* __restrict__ xout) {
    const int mt_of[20] = {0,1,2,2,3,3,4,4,4,5,5,5,6,6,6,6,7,7,7,7};
    const int kt_of[20] = {0,0,0,1,0,1,0,1,2,0,1,2,0,1,2,3,0,1,2,3};
    __shared__ __align__(16) short Gs[8192];   // [ekt 16][o 16][p 32] bf16 = 16KB
    __shared__ float dsm[NBN * EXPR * CTRL];   // 16KB
    int tid = threadIdx.x;
    int bid = blockIdx.x;                       // 512 = 16 on x 32 r, XCD-swizzled on r
    int r  = (bid & 7) * 4 + ((bid >> 3) & 3);
    int on = bid >> 5;                          // 0..15, 16-ocol slab

    // ---- stage B tiles (all e, all kt, 16 ocols) into LDS, frag order preserved
    #pragma unroll
    for (int it = 0; it < 4; ++it) {
        int c = it * 256 + tid;                 // 0..1023 16B-chunks
        int ekt = c >> 6;
        int o = (c >> 2) & 15;
        int h = c & 3;
        const short* src = Gbf + (((size_t)(r * 16 + ekt) * 256 + on * 16 + o) * 32 + h * 8);
        __builtin_amdgcn_global_load_lds(
            (__attribute__((address_space(1))) const void*)src,
            (__attribute__((address_space(3))) void*)(&Gs[c * 8]), 16, 0, 0);
    }
    for (int i = tid; i < NBN * EXPR * CTRL / 4; i += 256)
        ((float4*)dsm)[i] = ((const float4*)dfr)[i];
    __syncthreads();

    int l = tid & 63, w = tid >> 6;             // w = bn-pair index
    int n = l & 15, g4 = l >> 4;
    int ocol = on * 16 + n;
    float co = ((float)ocol + 0.5f) * (1.0f / 256.0f) - 0.5f;

    // ---- B-frags from LDS (conflict-free ds_read_b128), cached in regs
    bf16x8 bfr[4][4];                            // [e][kt]
    #pragma unroll
    for (int e = 0; e < 4; ++e)
        #pragma unroll
        for (int kt = 0; kt < 4; ++kt)
            bfr[e][kt] = *(const bf16x8*)&Gs[(e * 4 + kt) * 512 + n * 32 + g4 * 8];

    for (int bi = 0; bi < 2; ++bi) {
        int bn = w * 2 + bi;
        f32x4 acc[4][8] = {};
        const short* wfb = Wf + ((size_t)((r * 8 + bn) * 20)) * 512 + l * 8;
        #pragma unroll
        for (int pr = 0; pr < 20; ++pr) {
            bf16x8 wv = *(const bf16x8*)(wfb + pr * 512);
            int mt = mt_of[pr], kt = kt_of[pr];
            #pragma unroll
            for (int e = 0; e < 4; ++e)
                acc[e][mt] = __builtin_amdgcn_mfma_f32_16x16x32_bf16(wv, bfr[e][kt], acc[e][mt], 0, 0, 0);
        }
        // epilogue: de-lerp + e-sum + bf16 store
        __hip_bfloat16* xo = xout + (size_t)(bn * N_RES + r) * N_SAMPLES;
        #pragma unroll
        for (int mt = 0; mt < 8; ++mt) {
            #pragma unroll
            for (int q = 0; q < 4; ++q) {
                int j = mt * 16 + g4 * 4 + q;
                float pos = fminf(fmaxf((float)j + co, 0.0f), 127.0f);
                int lo = (int)floorf(pos);
                int hi = min(lo + 1, 127);
                float wg = pos - (float)lo;
                float x = 0.f;
                #pragma unroll
                for (int e = 0; e < 4; ++e) {
                    const float* dp = dsm + (bn * EXPR + e) * CTRL;
                    float de = dp[lo] * (1.0f - wg) + dp[hi] * wg;
                    x = fmaf(de, acc[e][mt][q], x);
                }
                xo[j * STEP + ocol] = __float2bfloat16(x);
            }
        }
    }
}

// ---------------------------------------------------------------- K6: tanh(gain*x) summed over r
__global__ __launch_bounds__(256) void k6_out(const __hip_bfloat16* __restrict__ xin,
                                              const float* __restrict__ gains,
                                              float* __restrict__ out) {
    __shared__ float gabs[N_RES];
    int bid = blockIdx.x;
    int sc = bid & 127, bn = bid >> 7;
    int o = threadIdx.x;
    if (o < N_RES) gabs[o] = fabsf(gains[o]);
    __syncthreads();
    int s = sc * STEP + o;
    float acc = 0.f;
    #pragma unroll 4
    for (int rr = 0; rr < N_RES; ++rr) {
        float xf = __bfloat162float(xin[(size_t)(bn * N_RES + rr) * N_SAMPLES + s]);
        acc += tanhf(xf * gabs[rr]);
    }
    out[bn * N_SAMPLES + s] = acc;
}

// ---------------------------------------------------------------- launch
extern "C" void kernel_launch(void* const* d_in, const int* in_sizes, int n_in,
                              void* d_out, int out_size, void* d_ws, size_t ws_size,
                              hipStream_t stream) {
    const float* control = (const float*)d_in[0];
    const float* defo    = (const float*)d_in[1];
    const float* router  = (const float*)d_in[2];
    const float* gains   = (const float*)d_in[3];
    const float* amp     = (const float*)d_in[4];
    const float* phase   = (const float*)d_in[5];
    const float* decay   = (const float*)d_in[6];
    const float* noise   = (const float*)d_in[7];

    float* out_summed = (float*)d_out;
    float* out_w      = (float*)d_out + NBN * N_SAMPLES;

    // ws layout:
    //  slot0 [0, 18.87MB): Bbf (k0b->k1m). After k1m dead: Gbf bf16 frag-order (8MB, k3->k5m)
    //                      + Wf bf16 (5.25MB at +8MB, k4w->k5m)
    //  slot1 [18.87, 35.65MB): res_raw f32 (k1m->k3); Pa/Za/L2a alias (dead before k1m);
    //                          xout bf16 alias (k5m->k6)
    //  tail: Afrag 294912B, normp 4KB, inv_norm 512B, dfr 16KB
    char* ws = (char*)d_ws;
    const size_t BSZ = (size_t)128 * NKS * 128 * 32 * 2;       // 18,874,368
    const size_t RSZ = (size_t)N_RES * EXPR * N_SAMPLES * 4;   // 16,777,216
    __hip_bfloat16* Bbf = (__hip_bfloat16*)ws;
    short* Gbf = (short*)ws;                                   // 8,388,608 B
    short* Wf  = (short*)(ws + 8388608);                       // 5,242,880 B
    char* slot1 = ws + BSZ;
    float* res_raw = (float*)slot1;
    float* Pa  = (float*)slot1;
    float* Za  = Pa + 128 * KT;
    float* L2a = Za + 128 * KT;
    __hip_bfloat16* xout = (__hip_bfloat16*)slot1;
    char* tail = slot1 + RSZ;
    __hip_bfloat16* Afrag = (__hip_bfloat16*)tail;             // 147456 elts
    float* normp = (float*)(tail + 294912);                    // 1024 floats
    float* inv_norm = normp + 1024;                            // 128 floats
    float* dfr = inv_norm + 128;                               // 4096 floats

    k0_params<<<288, 256, 0, stream>>>(amp, phase, decay, Pa, Za, L2a);
    k0a_afrag<<<576, 256, 0, stream>>>(Afrag);
    k0b_bgen<<<36864, 256, 0, stream>>>(Pa, Za, L2a, Bbf);
    k4a_route<<<(NBN * N_RES * CTRL) / 256, 256, 0, stream>>>(control, router, out_w);
    k4b_dfr<<<(NBN * CTRL + 255) / 256, 256, 0, stream>>>(defo, dfr);
    k1m<<<1024, 256, 0, stream>>>((const short*)Afrag, (const short*)Bbf, res_raw, normp);
    k2_fin<<<1, 128, 0, stream>>>(normp, inv_norm);
    k4w<<<1280, 256, 0, stream>>>(out_w, Wf);
    k3_impconv<<<N_RES * N_FRAMES, 256, 0, stream>>>(res_raw, inv_norm, noise, Gbf);
    k5m<<<512, 256, 0, stream>>>(Gbf, Wf, dfr, xout);
    k6_out<<<NBN * N_FRAMES, 256, 0, stream>>>(xout, gains, out_summed);
}